// Round 4
// baseline (316.235 us; speedup 1.0000x reference)
//
#include <hip/hip_runtime.h>
#include <hip/hip_bf16.h>

typedef __hip_bfloat16 bf16;
typedef short bf16x8 __attribute__((ext_vector_type(8)));
typedef short s16x4  __attribute__((ext_vector_type(4)));
typedef float f32x4  __attribute__((ext_vector_type(4)));

#define CHK 2048

__device__ __forceinline__ float bf2f(bf16 v){ return __bfloat162float(v); }
__device__ __forceinline__ bf16  f2bf(float f){ return __float2bfloat16(f); }
__device__ __forceinline__ float lrelu(float a){ return a > 0.f ? a : 0.2f*a; }
__device__ __forceinline__ float bfbits(short s){
    union{unsigned u; float f;} cv; cv.u = ((unsigned)(unsigned short)s) << 16; return cv.f;
}
__device__ __forceinline__ short bf16s(float f){ bf16 q = f2bf(f); return *(short*)&q; }
// polymorphic scalar reads (isb wave-uniform)
__device__ __forceinline__ float cvtf(const void* p, int i, int isb){
    return isb ? bf2f(((const bf16*)p)[i]) : ((const float*)p)[i];
}
__device__ __forceinline__ short cvts(const void* p, int i, int isb){
    return isb ? ((const short*)p)[i] : bf16s(((const float*)p)[i]);
}
// load 8 contiguous values as bf16x8 from either bf16 or f32 source
__device__ __forceinline__ bf16x8 load8(const void* base, size_t off, int isb){
    if (isb) return *(const bf16x8*)((const bf16*)base + off);
    const float* f = (const float*)base + off;
    f32x4 v0 = *(const f32x4*)f;
    f32x4 v1 = *(const f32x4*)(f + 4);
    short r[8];
    #pragma unroll
    for (int j = 0; j < 4; j++) r[j]   = bf16s(v0[j]);
    #pragma unroll
    for (int j = 0; j < 4; j++) r[4+j] = bf16s(v1[j]);
    return *(const bf16x8*)r;
}

// ---------------- init: dtype detect (block 0) + coarse bucket histogram of dst ----------------
__global__ __launch_bounds__(256) void k_init(const unsigned short* __restrict__ raw,
        int* __restrict__ flag, const int* __restrict__ dst,
        int* __restrict__ bucketCnt, int E, int NBUK, int nBlk){
    __shared__ int h[256];
    int t = threadIdx.x;
    if (blockIdx.x == 0){
        unsigned short w = raw[2*t];
        int e = (w >> 7) & 0xFF;
        int ok = (e >= 90 && e <= 140) ? 1 : 0;
        __shared__ int cnt;
        if (t == 0) cnt = 0;
        __syncthreads();
        atomicAdd(&cnt, ok);
        __syncthreads();
        if (t == 0) *flag = (cnt >= 192) ? 1 : 0;  // 1 = bf16, 0 = f32
    }
    h[t] = 0;
    __syncthreads();
    for (int i = blockIdx.x*256 + t; i < E; i += nBlk*256)
        atomicAdd(&h[((unsigned)dst[i]) >> 8], 1);
    __syncthreads();
    if (t < NBUK && h[t]) atomicAdd(&bucketCnt[t], h[t]);
}

// ---------------- prep: emb (blocks<nEmb, 4 tiles each) | pack W1 ----------------
__global__ __launch_bounds__(256) void k_prep(const void* __restrict__ low,
        const void* __restrict__ Wemb, const void* __restrict__ bemb,
        const void* __restrict__ W1,
        bf16* __restrict__ emb, bf16* __restrict__ Bp,
        const int* __restrict__ flag, int N, int nEmb){
    __shared__ float wem[2048 + 64];
    __shared__ short lows[1024];
    int t = threadIdx.x;
    int b = blockIdx.x;
    int isb = *flag;
    if (b >= nEmb){
        // pack role: W1 -> MFMA B-fragment layout
        int i = (b - nEmb)*256 + t;
        if (i < 16*6*64*8){
            int j = i & 7;
            int lane = (i >> 3) & 63;
            int r = i >> 9;
            int kt = r % 6, nt = r / 6;
            int k = kt*32 + (lane >> 4)*8 + j;
            int n = nt*16 + (lane & 15);
            *(short*)&Bp[i] = cvts(W1, k*256 + n, isb);
        }
        return;
    }
    // embedding role: four 32-node tiles sharing one W_emb load
    for (int i = t; i < 2048; i += 256) wem[i] = cvtf(Wemb, i, isb);
    if (t < 64) wem[2048 + t] = cvtf(bemb, t, isb);
    int nl = t >> 3, j8 = (t & 7) * 8;
    for (int tile = 0; tile < 4; tile++){
        int nb0 = b*128 + tile*32;
        __syncthreads();   // wem ready (tile 0) / previous tile compute done
        int lim = (N - nb0) * 32;
        if (lim > 1024) lim = 1024;
        if (lim < 0) lim = 0;
        for (int i = t; i < 1024; i += 256)
            lows[i] = (i < lim) ? cvts(low, nb0*32 + i, isb) : (short)0;
        __syncthreads();
        float acc[8];
        #pragma unroll
        for (int j = 0; j < 8; j++) acc[j] = wem[2048 + j8 + j];
        for (int k = 0; k < 32; k++){
            float lv = bfbits(lows[nl*32 + k]);
            f32x4 w0 = *(const f32x4*)&wem[k*64 + j8];
            f32x4 w1 = *(const f32x4*)&wem[k*64 + j8 + 4];
            #pragma unroll
            for (int j = 0; j < 4; j++) acc[j]   += lv * w0[j];
            #pragma unroll
            for (int j = 0; j < 4; j++) acc[4+j] += lv * w1[j];
        }
        int n = nb0 + nl;
        if (n < N){
            short ov[8];
            #pragma unroll
            for (int j = 0; j < 8; j++){
                float v = acc[j];
                ov[j] = bf16s(v > 0.f ? v : expm1f(v));
            }
            *(bf16x8*)&emb[(size_t)n*64 + j8] = *(const bf16x8*)ov;
        }
    }
}

// ---------------- single-block scan of coarse bucket counts ----------------
__global__ __launch_bounds__(256) void k_bscan(const int* __restrict__ bucketCnt,
        int* __restrict__ bucketPtr, int* __restrict__ bucketCur,
        int* __restrict__ rowptr, int N, int E, int NBUK){
    __shared__ int sd[256];
    int t = threadIdx.x;
    int v = (t < NBUK) ? bucketCnt[t] : 0;
    sd[t] = v;
    __syncthreads();
    #pragma unroll
    for (int off = 1; off < 256; off <<= 1){
        int a = (t >= off) ? sd[t - off] : 0;
        __syncthreads();
        sd[t] += a;
        __syncthreads();
    }
    int excl = sd[t] - v;
    if (t < NBUK){ bucketPtr[t] = excl; bucketCur[t*16] = excl; }  // cur strided: 1 int / 64B
    if (t == 0){ bucketPtr[NBUK] = sd[255]; rowptr[N] = E + N; }
}

// ---------------- merged: bucketed edge scatter (blocks < nScat) | GEMM1 (LDS-staged A) ----------------
__global__ __launch_bounds__(256) void k_sg(
        const int* __restrict__ ei, int* __restrict__ bucketCur, int* __restrict__ pk,
        const void* __restrict__ highv, const bf16* __restrict__ emb,
        const bf16* __restrict__ Bp, const void* __restrict__ attS,
        const void* __restrict__ attD, bf16* __restrict__ h1,
        float* __restrict__ a_s, float* __restrict__ a_d,
        const int* __restrict__ flag, int N, int E, int nScat, int NBUK){
    const int RS = 260;
    __shared__ union SM {
        struct { short Ah[64*128]; short Ae[64*64]; } a;                        // 24576B
        struct { float eb[16*260 + 16]; } g;                                     // 16704B (aliases Ah)
        struct { unsigned short dstS[CHK]; int hist[4][256]; int cur[4][256]; } s;// 12288B
    } sm;
    __shared__ float att[512];
    int t = threadIdx.x;
    if ((int)blockIdx.x < nScat){
        // ---- bucketed scatter role: pack (dstLow<<24 | src) grouped by dst>>8 ----
        int base = blockIdx.x * CHK;
        int cnt = E - base; if (cnt > CHK) cnt = CHK;
        int wv = t >> 6, lane = t & 63;
        #pragma unroll
        for (int w = 0; w < 4; w++) sm.s.hist[w][t] = 0;
        __syncthreads();
        const int* dstp = ei + E + base;
        const int* srcp = ei + base;
        int per = (cnt + 3) >> 2;
        int wb = wv*per, we = wb + per;
        if (we > cnt) we = cnt;
        if (wb > cnt) wb = cnt;
        for (int i = wb + lane; i < we; i += 64){
            int d = dstp[i];
            sm.s.dstS[i] = (unsigned short)d;
            atomicAdd(&sm.s.hist[wv][((unsigned)d) >> 8], 1);   // wave-private
        }
        __syncthreads();
        if (t < NBUK){
            int h0 = sm.s.hist[0][t], h1v = sm.s.hist[1][t];
            int h2 = sm.s.hist[2][t], h3 = sm.s.hist[3][t];
            int c = h0 + h1v + h2 + h3;
            int bs = c ? atomicAdd(&bucketCur[t*16], c) : 0;
            sm.s.cur[0][t] = bs;
            sm.s.cur[1][t] = bs + h0;
            sm.s.cur[2][t] = bs + h0 + h1v;
            sm.s.cur[3][t] = bs + h0 + h1v + h2;
        }
        __syncthreads();
        for (int i = wb + lane; i < we; i += 64){
            int d = sm.s.dstS[i];
            int pos = atomicAdd(&sm.s.cur[wv][d >> 8], 1);      // wave-private
            pk[pos] = ((d & 255) << 24) | srcp[i];
        }
        return;
    }
    // ---- GEMM1 role ----
    int isb = *flag;
    att[t] = cvtf(attS, t, isb);
    att[256 + t] = cvtf(attD, t, isb);
    int w = t >> 6, lane = t & 63;
    int m_lo = lane & 15, quad = lane >> 4;
    int m0 = (blockIdx.x - nScat) * 64;

    // ---- stage A (high 64x128 + emb 64x64) into XOR-swizzled LDS, coalesced ----
    #pragma unroll
    for (int ii = 0; ii < 4; ii++){
        int id = t + ii*256;            // 0..1023
        int r = id >> 4, c = id & 15;
        int gr = m0 + r; if (gr >= N) gr = N-1;
        bf16x8 v = load8(highv, (size_t)gr*128 + c*8, isb);
        *(bf16x8*)&sm.a.Ah[r*128 + ((c ^ (r & 7)) << 3)] = v;
    }
    #pragma unroll
    for (int ii = 0; ii < 2; ii++){
        int id = t + ii*256;            // 0..511
        int r = id >> 3, c = id & 7;
        int gr = m0 + r; if (gr >= N) gr = N-1;
        bf16x8 v = *(const bf16x8*)&emb[(size_t)gr*64 + c*8];
        *(bf16x8*)&sm.a.Ae[r*64 + ((c ^ (r & 7)) << 3)] = v;
    }
    __syncthreads();

    f32x4 acc[4][4];
    #pragma unroll
    for (int rt = 0; rt < 4; rt++)
        #pragma unroll
        for (int ct = 0; ct < 4; ct++) acc[rt][ct] = (f32x4){0.f,0.f,0.f,0.f};

    int sw = m_lo & 7;   // row-XOR for fragment reads
    #pragma unroll 2
    for (int kt = 0; kt < 6; kt++){
        bf16x8 a[4], b[4];
        if (kt < 4){
            int ch = (kt*4 + quad) ^ sw;
            #pragma unroll
            for (int rt = 0; rt < 4; rt++)
                a[rt] = *(const bf16x8*)&sm.a.Ah[(rt*16 + m_lo)*128 + (ch << 3)];
        } else {
            int ch = ((kt-4)*4 + quad) ^ sw;
            #pragma unroll
            for (int rt = 0; rt < 4; rt++)
                a[rt] = *(const bf16x8*)&sm.a.Ae[(rt*16 + m_lo)*64 + (ch << 3)];
        }
        #pragma unroll
        for (int ct = 0; ct < 4; ct++)
            b[ct] = *(const bf16x8*)&Bp[(size_t)(((w*4 + ct)*6 + kt)*64 + lane)*8];
        #pragma unroll
        for (int rt = 0; rt < 4; rt++)
            #pragma unroll
            for (int ct = 0; ct < 4; ct++)
                acc[rt][ct] = __builtin_amdgcn_mfma_f32_16x16x32_bf16(a[rt], b[ct], acc[rt][ct], 0, 0, 0);
    }

    float* eb = sm.g.eb;   // aliases Ah — safe: barriers below separate all uses
    #pragma unroll 1
    for (int rt = 0; rt < 4; rt++){
        __syncthreads();
        #pragma unroll
        for (int ct = 0; ct < 4; ct++)
            #pragma unroll
            for (int reg = 0; reg < 4; reg++)
                eb[(quad*4 + reg)*RS + w*64 + ct*16 + m_lo] = acc[rt][ct][reg];
        __syncthreads();
        int r = t >> 4, cb = t & 15;
        int c0 = cb * 16;
        int m = m0 + rt*16 + r;
        f32x4 v[4];
        #pragma unroll
        for (int p = 0; p < 4; p++) v[p] = *(const f32x4*)&eb[r*RS + c0 + p*4];
        float ps = 0.f, pd = 0.f;
        #pragma unroll
        for (int p = 0; p < 4; p++)
            #pragma unroll
            for (int j = 0; j < 4; j++){
                ps += v[p][j] * att[c0 + p*4 + j];
                pd += v[p][j] * att[256 + c0 + p*4 + j];
            }
        if (m < N){
            short ov[16];
            #pragma unroll
            for (int p = 0; p < 4; p++)
                #pragma unroll
                for (int j = 0; j < 4; j++) ov[p*4+j] = bf16s(v[p][j]);
            *(bf16x8*)&h1[(size_t)m*256 + c0]     = *(const bf16x8*)&ov[0];
            *(bf16x8*)&h1[(size_t)m*256 + c0 + 8] = *(const bf16x8*)&ov[8];
        }
        ps += __shfl_xor(ps, 1);
        pd += __shfl_xor(pd, 1);
        if (((t & 1) == 0) && m < N){
            int hd = cb >> 1;
            a_s[m*8 + hd] = ps;
            a_d[m*8 + hd] = pd;
        }
    }
}

// ---------------- fine pass: per-bucket dst counts (wave-private), scan, self-loops, final scatter ----------------
__global__ __launch_bounds__(256) void k_fine(const int* __restrict__ bucketPtr,
        const int* __restrict__ pk, int* __restrict__ rowptr, int* __restrict__ srcs,
        int N){
    __shared__ int hist[4][256];
    __shared__ int cur[4][256];
    __shared__ int sd[256];
    int t = threadIdx.x;
    int wv = t >> 6, lane = t & 63;
    int b = blockIdx.x;
    int d0 = b << 8;
    int nd = N - d0; if (nd > 256) nd = 256; if (nd < 0) nd = 0;
    int ebeg = bucketPtr[b], eend = bucketPtr[b+1];
    int tot = eend - ebeg;
    int per = (tot + 3) >> 2;
    int wb = wv*per, we = wb + per;
    if (we > tot) we = tot;
    if (wb > tot) wb = tot;
    #pragma unroll
    for (int w = 0; w < 4; w++) hist[w][t] = 0;
    __syncthreads();
    for (int i = wb + lane; i < we; i += 64)
        atomicAdd(&hist[wv][((unsigned)pk[ebeg + i]) >> 24], 1);   // wave-private
    __syncthreads();
    int h0 = hist[0][t], h1 = hist[1][t], h2 = hist[2][t], h3 = hist[3][t];
    int selfc = (t < nd) ? 1 : 0;
    int v = selfc + h0 + h1 + h2 + h3;
    sd[t] = v;
    __syncthreads();
    #pragma unroll
    for (int off = 1; off < 256; off <<= 1){
        int a = (t >= off) ? sd[t - off] : 0;
        __syncthreads();
        sd[t] += a;
        __syncthreads();
    }
    int r = ebeg + d0 + sd[t] - v;   // prior self-loops = d0 (all earlier buckets full)
    if (t < nd){
        rowptr[d0 + t] = r;
        srcs[r] = d0 + t;            // self-loop at segment head
    }
    int c0 = r + selfc;
    cur[0][t] = c0;
    cur[1][t] = c0 + h0;
    cur[2][t] = c0 + h0 + h1;
    cur[3][t] = c0 + h0 + h1 + h2;
    __syncthreads();
    for (int i = wb + lane; i < we; i += 64){
        int p = pk[ebeg + i];
        int pos = atomicAdd(&cur[wv][((unsigned)p) >> 24], 1);     // wave-private
        srcs[pos] = p & 0xFFFFFF;
    }
}

// ---------------- layer-1 aggregate (lane-specialized weights) + elu + FUSED layer-2 GEMV ----------------
__global__ __launch_bounds__(256) void k_edge1(const int* __restrict__ rowptr,
        const int* __restrict__ srcs, const float* __restrict__ a_s,
        const float* __restrict__ a_d, const bf16* __restrict__ h1,
        const void* __restrict__ b1, const void* __restrict__ W2,
        const void* __restrict__ attS2, const void* __restrict__ attD2,
        float* __restrict__ h2, float* __restrict__ a2s, float* __restrict__ a2d,
        const int* __restrict__ flag, int N){
    int t = threadIdx.x;
    int lane = t & 63, wv = t >> 6;
    int n = blockIdx.x*4 + wv;
    if (n >= N) return;
    int beg = rowptr[n];
    int deg = rowptr[n+1] - beg;

    int cl = lane & 31;          // channel group: channels cl*8..cl*8+7
    int hb = cl >> 2;            // head of this group
    int half = lane >> 5;        // edge parity within chunk
    int eL = lane & 7, hL = lane >> 3;   // weight-lane role: edge eL, head hL
    float adW = a_d[n*8 + hL];

    float acc[8];
    #pragma unroll
    for (int j = 0; j < 8; j++) acc[j] = 0.f;
    float zL = 0.f;

    for (int e0 = 0; e0 < deg; e0 += 8){
        int ew = e0 + eL;
        int sw = srcs[beg + (ew < deg ? ew : 0)];
        float wgt = 0.f;
        if (ew < deg)
            wgt = __expf(fminf(lrelu(a_s[sw*8 + hL] + adW), 80.f));
        zL += wgt;
        // redistribute: aggregation edge set {half, half+2, half+4, half+6}
        int s0 = __shfl(sw, half);
        int s1 = __shfl(sw, half + 2);
        int s2 = __shfl(sw, half + 4);
        int s3 = __shfl(sw, half + 6);
        float w0 = __shfl(wgt, hb*8 + half);
        float w1 = __shfl(wgt, hb*8 + half + 2);
        float w2 = __shfl(wgt, hb*8 + half + 4);
        float w3 = __shfl(wgt, hb*8 + half + 6);
        bf16x8 v0 = *(const bf16x8*)&h1[(size_t)s0*256 + cl*8];
        bf16x8 v1 = *(const bf16x8*)&h1[(size_t)s1*256 + cl*8];
        bf16x8 v2 = *(const bf16x8*)&h1[(size_t)s2*256 + cl*8];
        bf16x8 v3 = *(const bf16x8*)&h1[(size_t)s3*256 + cl*8];
        #pragma unroll
        for (int j = 0; j < 8; j++) acc[j] += w0 * bfbits(v0[j]);
        #pragma unroll
        for (int j = 0; j < 8; j++) acc[j] += w1 * bfbits(v1[j]);
        #pragma unroll
        for (int j = 0; j < 8; j++) acc[j] += w2 * bfbits(v2[j]);
        #pragma unroll
        for (int j = 0; j < 8; j++) acc[j] += w3 * bfbits(v3[j]);
    }
    // z: reduce within 8-lane head group (bits 0..2)
    zL += __shfl_xor(zL, 1);
    zL += __shfl_xor(zL, 2);
    zL += __shfl_xor(zL, 4);
    #pragma unroll
    for (int j = 0; j < 8; j++) acc[j] += __shfl_xor(acc[j], 32);
    float zh = __shfl(zL, hb*8);
    float rz = 1.f / (zh + 1e-16f);

    int isb = *flag;
    bf16x8 bv = load8(b1, cl*8, isb);
    float xv[8];
    #pragma unroll
    for (int j = 0; j < 8; j++){
        float v = acc[j] * rz + bfbits(bv[j]);
        xv[j] = v > 0.f ? v : expm1f(v);
    }
    // ---- fused layer-2 GEMV: h2[n][o] = sum_c xv[c]*W2[c][o]; lane covers o = half*4..half*4+3
    float p[4] = {0.f, 0.f, 0.f, 0.f};
    #pragma unroll
    for (int j = 0; j < 8; j++){
        int c = cl*8 + j;
        float wr[4];
        if (isb){
            s16x4 q = *(const s16x4*)((const bf16*)W2 + c*8 + half*4);
            #pragma unroll
            for (int o = 0; o < 4; o++) wr[o] = bfbits(q[o]);
        } else {
            f32x4 q = *(const f32x4*)((const float*)W2 + c*8 + half*4);
            #pragma unroll
            for (int o = 0; o < 4; o++) wr[o] = q[o];
        }
        #pragma unroll
        for (int o = 0; o < 4; o++) p[o] += xv[j] * wr[o];
    }
    #pragma unroll
    for (int o = 0; o < 4; o++){
        p[o] += __shfl_xor(p[o], 1);
        p[o] += __shfl_xor(p[o], 2);
        p[o] += __shfl_xor(p[o], 4);
        p[o] += __shfl_xor(p[o], 8);
        p[o] += __shfl_xor(p[o], 16);
    }
    float as2 = 0.f, ad2 = 0.f;
    #pragma unroll
    for (int o = 0; o < 4; o++){
        as2 += p[o] * cvtf(attS2, half*4 + o, isb);
        ad2 += p[o] * cvtf(attD2, half*4 + o, isb);
    }
    as2 += __shfl_xor(as2, 32);
    ad2 += __shfl_xor(ad2, 32);
    if (lane == 0){ a2s[n] = as2; a2d[n] = ad2; }
    if ((lane & 31) == 0)
        *(f32x4*)&h2[(size_t)n*8 + half*4] = (f32x4){p[0], p[1], p[2], p[3]};
}

// ---------------- layer-2: single-sweep aggregate + bias + log_softmax ----------------
__global__ __launch_bounds__(256) void k_edge2(const int* __restrict__ rowptr,
        const int* __restrict__ srcs, const float* __restrict__ a2s,
        const float* __restrict__ a2d, const float* __restrict__ h2,
        const void* __restrict__ b2, void* __restrict__ outv,
        const int* __restrict__ flag, int N){
    int t = threadIdx.x;
    int lane = t & 63, wv = t >> 6;
    int n = blockIdx.x*4 + wv;
    if (n >= N) return;
    int beg = rowptr[n];
    int deg = rowptr[n+1] - beg;
    float adh = a2d[n];
    int ep = lane >> 3, c = lane & 7;
    float acc = 0.f, z = 0.f;
    for (int e = ep; e < deg; e += 8){
        int s = srcs[beg + e];
        float w = __expf(fminf(lrelu(a2s[s] + adh), 80.f));
        z += w;
        acc += w * h2[(size_t)s*8 + c];
    }
    acc += __shfl_xor(acc, 8);
    acc += __shfl_xor(acc, 16);
    acc += __shfl_xor(acc, 32);
    z += __shfl_xor(z, 8);
    z += __shfl_xor(z, 16);
    z += __shfl_xor(z, 32);
    int isb = *flag;
    float val = acc / (z + 1e-16f) + cvtf(b2, c, isb);
    float mx = val;
    mx = fmaxf(mx, __shfl_xor(mx, 1));
    mx = fmaxf(mx, __shfl_xor(mx, 2));
    mx = fmaxf(mx, __shfl_xor(mx, 4));
    float se = __expf(val - mx);
    se += __shfl_xor(se, 1); se += __shfl_xor(se, 2); se += __shfl_xor(se, 4);
    float r = val - mx - __logf(se);
    if (lane < 8){
        if (isb) ((bf16*)outv)[(size_t)n*8 + c] = f2bf(r);
        else     ((float*)outv)[(size_t)n*8 + c] = r;
    }
}

extern "C" void kernel_launch(void* const* d_in, const int* in_sizes, int n_in,
                              void* d_out, int out_size, void* d_ws, size_t ws_size,
                              hipStream_t stream) {
    const int* ei = (const int*)d_in[2];
    const int N = in_sizes[0] / 128;
    const int E = in_sizes[2] / 2;
    const int ET = E + N;
    const int NBUK = (N + 255) >> 8;

    char* p = (char*)d_ws;
    auto alloc = [&](size_t bytes) -> void* {
        char* r = p;
        p += (bytes + 255) & ~(size_t)255;
        return (void*)r;
    };
    int*   flag      = (int*)  alloc(256);
    int*   bucketCnt = (int*)  alloc((size_t)NBUK*4);
    int*   bucketPtr = (int*)  alloc((size_t)(NBUK+1)*4);
    int*   bucketCur = (int*)  alloc((size_t)NBUK*16*4);   // strided: 1 int per 64B
    int*   rowptr    = (int*)  alloc((size_t)(N+1)*4);
    int*   srcs      = (int*)  alloc((size_t)ET*4);
    int*   pk        = (int*)  alloc((size_t)E*4);
    bf16*  Bp        = (bf16*) alloc((size_t)192*256*2);
    bf16*  emb       = (bf16*) alloc((size_t)N*64*2);
    bf16*  h1        = (bf16*) alloc((size_t)N*256*2);
    float* a_s       = (float*)alloc((size_t)N*8*4);
    float* a_d       = (float*)alloc((size_t)N*8*4);
    float* h2        = (float*)alloc((size_t)N*8*4);
    float* a2s       = (float*)alloc((size_t)N*4);
    float* a2d      = (float*)alloc((size_t)N*4);

    hipMemsetAsync(bucketCnt, 0, (size_t)NBUK*4, stream);
    k_init<<<256, 256, 0, stream>>>((const unsigned short*)d_in[0], flag,
            ei + E, bucketCnt, E, NBUK, 256);
    {
        int nEmb  = (N + 127)/128;
        int nPack = (16*6*64*8)/256;
        k_prep<<<nEmb + nPack, 256, 0, stream>>>(d_in[1], d_in[3], d_in[4],
                d_in[5], emb, Bp, flag, N, nEmb);
    }
    k_bscan<<<1, 256, 0, stream>>>(bucketCnt, bucketPtr, bucketCur, rowptr, N, E, NBUK);
    {
        int nG = (N + 63)/64;
        int nScat = (E + CHK - 1)/CHK;
        k_sg<<<nScat + nG, 256, 0, stream>>>(ei, bucketCur, pk,
                d_in[0], emb, Bp, d_in[6], d_in[7], h1, a_s, a_d, flag, N, E, nScat, NBUK);
    }
    k_fine<<<NBUK, 256, 0, stream>>>(bucketPtr, pk, rowptr, srcs, N);
    k_edge1<<<(N + 3)/4, 256, 0, stream>>>(rowptr, srcs, a_s, a_d, h1, d_in[8],
            d_in[9], d_in[10], d_in[11], h2, a2s, a2d, flag, N);
    k_edge2<<<(N + 3)/4, 256, 0, stream>>>(rowptr, srcs, a2s, a2d, h2, d_in[12], d_out, flag, N);
}

// Round 5
// 313.673 us; speedup vs baseline: 1.0082x; 1.0082x over previous
//
#include <hip/hip_runtime.h>
#include <hip/hip_bf16.h>

typedef __hip_bfloat16 bf16;
typedef short bf16x8 __attribute__((ext_vector_type(8)));
typedef short s16x4  __attribute__((ext_vector_type(4)));
typedef float f32x4  __attribute__((ext_vector_type(4)));

#define CHK 2048

__device__ __forceinline__ float bf2f(bf16 v){ return __bfloat162float(v); }
__device__ __forceinline__ bf16  f2bf(float f){ return __float2bfloat16(f); }
__device__ __forceinline__ float lrelu(float a){ return a > 0.f ? a : 0.2f*a; }
__device__ __forceinline__ float bfbits(short s){
    union{unsigned u; float f;} cv; cv.u = ((unsigned)(unsigned short)s) << 16; return cv.f;
}
__device__ __forceinline__ short bf16s(float f){ bf16 q = f2bf(f); return *(short*)&q; }
// polymorphic scalar reads (isb wave-uniform)
__device__ __forceinline__ float cvtf(const void* p, int i, int isb){
    return isb ? bf2f(((const bf16*)p)[i]) : ((const float*)p)[i];
}
__device__ __forceinline__ short cvts(const void* p, int i, int isb){
    return isb ? ((const short*)p)[i] : bf16s(((const float*)p)[i]);
}
// load 8 contiguous values as bf16x8 from either bf16 or f32 source
__device__ __forceinline__ bf16x8 load8(const void* base, size_t off, int isb){
    if (isb) return *(const bf16x8*)((const bf16*)base + off);
    const float* f = (const float*)base + off;
    f32x4 v0 = *(const f32x4*)f;
    f32x4 v1 = *(const f32x4*)(f + 4);
    short r[8];
    #pragma unroll
    for (int j = 0; j < 4; j++) r[j]   = bf16s(v0[j]);
    #pragma unroll
    for (int j = 0; j < 4; j++) r[4+j] = bf16s(v1[j]);
    return *(const bf16x8*)r;
}

// ---------------- init: dtype detect (block 0) + coarse bucket histogram of dst ----------------
__global__ __launch_bounds__(256) void k_init(const unsigned short* __restrict__ raw,
        int* __restrict__ flag, const int* __restrict__ dst,
        int* __restrict__ bucketCnt, int E, int NBUK, int nBlk){
    __shared__ int h[256];
    int t = threadIdx.x;
    if (blockIdx.x == 0){
        unsigned short w = raw[2*t];
        int e = (w >> 7) & 0xFF;
        int ok = (e >= 90 && e <= 140) ? 1 : 0;
        __shared__ int cnt;
        if (t == 0) cnt = 0;
        __syncthreads();
        atomicAdd(&cnt, ok);
        __syncthreads();
        if (t == 0) *flag = (cnt >= 192) ? 1 : 0;  // 1 = bf16, 0 = f32
    }
    h[t] = 0;
    __syncthreads();
    for (int i = blockIdx.x*256 + t; i < E; i += nBlk*256)
        atomicAdd(&h[((unsigned)dst[i]) >> 8], 1);
    __syncthreads();
    if (t < NBUK && h[t]) atomicAdd(&bucketCnt[t], h[t]);
}

// ---------------- prep: emb (blocks<nEmb, 4 tiles each) | pack W1 ----------------
__global__ __launch_bounds__(256) void k_prep(const void* __restrict__ low,
        const void* __restrict__ Wemb, const void* __restrict__ bemb,
        const void* __restrict__ W1,
        bf16* __restrict__ emb, bf16* __restrict__ Bp,
        const int* __restrict__ flag, int N, int nEmb){
    __shared__ float wem[2048 + 64];
    __shared__ short lows[1024];
    int t = threadIdx.x;
    int b = blockIdx.x;
    int isb = *flag;
    if (b >= nEmb){
        // pack role: W1 -> MFMA B-fragment layout
        int i = (b - nEmb)*256 + t;
        if (i < 16*6*64*8){
            int j = i & 7;
            int lane = (i >> 3) & 63;
            int r = i >> 9;
            int kt = r % 6, nt = r / 6;
            int k = kt*32 + (lane >> 4)*8 + j;
            int n = nt*16 + (lane & 15);
            *(short*)&Bp[i] = cvts(W1, k*256 + n, isb);
        }
        return;
    }
    // embedding role: four 32-node tiles sharing one W_emb load
    for (int i = t; i < 2048; i += 256) wem[i] = cvtf(Wemb, i, isb);
    if (t < 64) wem[2048 + t] = cvtf(bemb, t, isb);
    int nl = t >> 3, j8 = (t & 7) * 8;
    for (int tile = 0; tile < 4; tile++){
        int nb0 = b*128 + tile*32;
        __syncthreads();   // wem ready (tile 0) / previous tile compute done
        int lim = (N - nb0) * 32;
        if (lim > 1024) lim = 1024;
        if (lim < 0) lim = 0;
        for (int i = t; i < 1024; i += 256)
            lows[i] = (i < lim) ? cvts(low, nb0*32 + i, isb) : (short)0;
        __syncthreads();
        float acc[8];
        #pragma unroll
        for (int j = 0; j < 8; j++) acc[j] = wem[2048 + j8 + j];
        for (int k = 0; k < 32; k++){
            float lv = bfbits(lows[nl*32 + k]);
            f32x4 w0 = *(const f32x4*)&wem[k*64 + j8];
            f32x4 w1 = *(const f32x4*)&wem[k*64 + j8 + 4];
            #pragma unroll
            for (int j = 0; j < 4; j++) acc[j]   += lv * w0[j];
            #pragma unroll
            for (int j = 0; j < 4; j++) acc[4+j] += lv * w1[j];
        }
        int n = nb0 + nl;
        if (n < N){
            short ov[8];
            #pragma unroll
            for (int j = 0; j < 8; j++){
                float v = acc[j];
                ov[j] = bf16s(v > 0.f ? v : expm1f(v));
            }
            *(bf16x8*)&emb[(size_t)n*64 + j8] = *(const bf16x8*)ov;
        }
    }
}

// ---------------- single-block scan of coarse bucket counts ----------------
__global__ __launch_bounds__(256) void k_bscan(const int* __restrict__ bucketCnt,
        int* __restrict__ bucketPtr, int* __restrict__ bucketCur,
        int* __restrict__ rowptr, int N, int E, int NBUK){
    __shared__ int sd[256];
    int t = threadIdx.x;
    int v = (t < NBUK) ? bucketCnt[t] : 0;
    sd[t] = v;
    __syncthreads();
    #pragma unroll
    for (int off = 1; off < 256; off <<= 1){
        int a = (t >= off) ? sd[t - off] : 0;
        __syncthreads();
        sd[t] += a;
        __syncthreads();
    }
    int excl = sd[t] - v;
    if (t < NBUK){ bucketPtr[t] = excl; bucketCur[t*16] = excl; }  // cur strided: 1 int / 64B
    if (t == 0){ bucketPtr[NBUK] = sd[255]; rowptr[N] = E + N; }
}

// ---------------- merged: bucketed edge scatter (blocks < nScat) | GEMM1 (LDS-staged A) ----------------
__global__ __launch_bounds__(256) void k_sg(
        const int* __restrict__ ei, int* __restrict__ bucketCur, int* __restrict__ pk,
        const void* __restrict__ highv, const bf16* __restrict__ emb,
        const bf16* __restrict__ Bp, const void* __restrict__ attS,
        const void* __restrict__ attD, bf16* __restrict__ h1,
        float* __restrict__ a_s, float* __restrict__ a_d,
        const int* __restrict__ flag, int N, int E, int nScat, int NBUK){
    const int RS = 260;
    __shared__ union SM {
        struct { short Ah[64*128]; short Ae[64*64]; } a;                        // 24576B
        struct { float eb[16*260 + 16]; } g;                                     // 16704B (aliases Ah)
        struct { unsigned short dstS[CHK]; int hist[4][256]; int cur[4][256]; } s;// 12288B
    } sm;
    __shared__ float att[512];
    int t = threadIdx.x;
    if ((int)blockIdx.x < nScat){
        // ---- bucketed scatter role: pack (dstLow<<24 | src) grouped by dst>>8 ----
        int base = blockIdx.x * CHK;
        int cnt = E - base; if (cnt > CHK) cnt = CHK;
        int wv = t >> 6, lane = t & 63;
        #pragma unroll
        for (int w = 0; w < 4; w++) sm.s.hist[w][t] = 0;
        __syncthreads();
        const int* dstp = ei + E + base;
        const int* srcp = ei + base;
        int per = (cnt + 3) >> 2;
        int wb = wv*per, we = wb + per;
        if (we > cnt) we = cnt;
        if (wb > cnt) wb = cnt;
        for (int i = wb + lane; i < we; i += 64){
            int d = dstp[i];
            sm.s.dstS[i] = (unsigned short)d;
            atomicAdd(&sm.s.hist[wv][((unsigned)d) >> 8], 1);   // wave-private
        }
        __syncthreads();
        if (t < NBUK){
            int h0 = sm.s.hist[0][t], h1v = sm.s.hist[1][t];
            int h2 = sm.s.hist[2][t], h3 = sm.s.hist[3][t];
            int c = h0 + h1v + h2 + h3;
            int bs = c ? atomicAdd(&bucketCur[t*16], c) : 0;
            sm.s.cur[0][t] = bs;
            sm.s.cur[1][t] = bs + h0;
            sm.s.cur[2][t] = bs + h0 + h1v;
            sm.s.cur[3][t] = bs + h0 + h1v + h2;
        }
        __syncthreads();
        for (int i = wb + lane; i < we; i += 64){
            int d = sm.s.dstS[i];
            int pos = atomicAdd(&sm.s.cur[wv][d >> 8], 1);      // wave-private
            pk[pos] = ((d & 255) << 24) | srcp[i];
        }
        return;
    }
    // ---- GEMM1 role ----
    int isb = *flag;
    att[t] = cvtf(attS, t, isb);
    att[256 + t] = cvtf(attD, t, isb);
    int w = t >> 6, lane = t & 63;
    int m_lo = lane & 15, quad = lane >> 4;
    int m0 = (blockIdx.x - nScat) * 64;

    // ---- stage A (high 64x128 + emb 64x64) into XOR-swizzled LDS, coalesced ----
    #pragma unroll
    for (int ii = 0; ii < 4; ii++){
        int id = t + ii*256;            // 0..1023
        int r = id >> 4, c = id & 15;
        int gr = m0 + r; if (gr >= N) gr = N-1;
        bf16x8 v = load8(highv, (size_t)gr*128 + c*8, isb);
        *(bf16x8*)&sm.a.Ah[r*128 + ((c ^ (r & 7)) << 3)] = v;
    }
    #pragma unroll
    for (int ii = 0; ii < 2; ii++){
        int id = t + ii*256;            // 0..511
        int r = id >> 3, c = id & 7;
        int gr = m0 + r; if (gr >= N) gr = N-1;
        bf16x8 v = *(const bf16x8*)&emb[(size_t)gr*64 + c*8];
        *(bf16x8*)&sm.a.Ae[r*64 + ((c ^ (r & 7)) << 3)] = v;
    }
    __syncthreads();

    f32x4 acc[4][4];
    #pragma unroll
    for (int rt = 0; rt < 4; rt++)
        #pragma unroll
        for (int ct = 0; ct < 4; ct++) acc[rt][ct] = (f32x4){0.f,0.f,0.f,0.f};

    int sw = m_lo & 7;   // row-XOR for fragment reads
    #pragma unroll 2
    for (int kt = 0; kt < 6; kt++){
        bf16x8 a[4], b[4];
        if (kt < 4){
            int ch = (kt*4 + quad) ^ sw;
            #pragma unroll
            for (int rt = 0; rt < 4; rt++)
                a[rt] = *(const bf16x8*)&sm.a.Ah[(rt*16 + m_lo)*128 + (ch << 3)];
        } else {
            int ch = ((kt-4)*4 + quad) ^ sw;
            #pragma unroll
            for (int rt = 0; rt < 4; rt++)
                a[rt] = *(const bf16x8*)&sm.a.Ae[(rt*16 + m_lo)*64 + (ch << 3)];
        }
        #pragma unroll
        for (int ct = 0; ct < 4; ct++)
            b[ct] = *(const bf16x8*)&Bp[(size_t)(((w*4 + ct)*6 + kt)*64 + lane)*8];
        #pragma unroll
        for (int rt = 0; rt < 4; rt++)
            #pragma unroll
            for (int ct = 0; ct < 4; ct++)
                acc[rt][ct] = __builtin_amdgcn_mfma_f32_16x16x32_bf16(a[rt], b[ct], acc[rt][ct], 0, 0, 0);
    }

    float* eb = sm.g.eb;   // aliases Ah — safe: barriers below separate all uses
    #pragma unroll 1
    for (int rt = 0; rt < 4; rt++){
        __syncthreads();
        #pragma unroll
        for (int ct = 0; ct < 4; ct++)
            #pragma unroll
            for (int reg = 0; reg < 4; reg++)
                eb[(quad*4 + reg)*RS + w*64 + ct*16 + m_lo] = acc[rt][ct][reg];
        __syncthreads();
        int r = t >> 4, cb = t & 15;
        int c0 = cb * 16;
        int m = m0 + rt*16 + r;
        f32x4 v[4];
        #pragma unroll
        for (int p = 0; p < 4; p++) v[p] = *(const f32x4*)&eb[r*RS + c0 + p*4];
        float ps = 0.f, pd = 0.f;
        #pragma unroll
        for (int p = 0; p < 4; p++)
            #pragma unroll
            for (int j = 0; j < 4; j++){
                ps += v[p][j] * att[c0 + p*4 + j];
                pd += v[p][j] * att[256 + c0 + p*4 + j];
            }
        if (m < N){
            short ov[16];
            #pragma unroll
            for (int p = 0; p < 4; p++)
                #pragma unroll
                for (int j = 0; j < 4; j++) ov[p*4+j] = bf16s(v[p][j]);
            *(bf16x8*)&h1[(size_t)m*256 + c0]     = *(const bf16x8*)&ov[0];
            *(bf16x8*)&h1[(size_t)m*256 + c0 + 8] = *(const bf16x8*)&ov[8];
        }
        ps += __shfl_xor(ps, 1);
        pd += __shfl_xor(pd, 1);
        if (((t & 1) == 0) && m < N){
            int hd = cb >> 1;
            a_s[m*8 + hd] = ps;
            a_d[m*8 + hd] = pd;
        }
    }
}

// ---------------- fine pass: per-bucket dst counts (wave-private), scan, self-loops, final scatter ----------------
__global__ __launch_bounds__(256) void k_fine(const int* __restrict__ bucketPtr,
        const int* __restrict__ pk, int* __restrict__ rowptr, int* __restrict__ srcs,
        int N){
    __shared__ int hist[4][256];
    __shared__ int cur[4][256];
    __shared__ int sd[256];
    int t = threadIdx.x;
    int wv = t >> 6, lane = t & 63;
    int b = blockIdx.x;
    int d0 = b << 8;
    int nd = N - d0; if (nd > 256) nd = 256; if (nd < 0) nd = 0;
    int ebeg = bucketPtr[b], eend = bucketPtr[b+1];
    int tot = eend - ebeg;
    int per = (tot + 3) >> 2;
    int wb = wv*per, we = wb + per;
    if (we > tot) we = tot;
    if (wb > tot) wb = tot;
    #pragma unroll
    for (int w = 0; w < 4; w++) hist[w][t] = 0;
    __syncthreads();
    for (int i = wb + lane; i < we; i += 64)
        atomicAdd(&hist[wv][((unsigned)pk[ebeg + i]) >> 24], 1);   // wave-private
    __syncthreads();
    int h0 = hist[0][t], h1 = hist[1][t], h2 = hist[2][t], h3 = hist[3][t];
    int selfc = (t < nd) ? 1 : 0;
    int v = selfc + h0 + h1 + h2 + h3;
    sd[t] = v;
    __syncthreads();
    #pragma unroll
    for (int off = 1; off < 256; off <<= 1){
        int a = (t >= off) ? sd[t - off] : 0;
        __syncthreads();
        sd[t] += a;
        __syncthreads();
    }
    int r = ebeg + d0 + sd[t] - v;   // prior self-loops = d0 (all earlier buckets full)
    if (t < nd){
        rowptr[d0 + t] = r;
        srcs[r] = d0 + t;            // self-loop at segment head
    }
    int c0 = r + selfc;
    cur[0][t] = c0;
    cur[1][t] = c0 + h0;
    cur[2][t] = c0 + h0 + h1;
    cur[3][t] = c0 + h0 + h1 + h2;
    __syncthreads();
    for (int i = wb + lane; i < we; i += 64){
        int p = pk[ebeg + i];
        int pos = atomicAdd(&cur[wv][((unsigned)p) >> 24], 1);     // wave-private
        srcs[pos] = p & 0xFFFFFF;
    }
}

// ---------------- layer-1 aggregate (R3 inner loop) + elu + FUSED layer-2 GEMV ----------------
__global__ __launch_bounds__(256) void k_edge1(const int* __restrict__ rowptr,
        const int* __restrict__ srcs, const float* __restrict__ a_s,
        const float* __restrict__ a_d, const bf16* __restrict__ h1,
        const void* __restrict__ b1, const void* __restrict__ W2,
        const void* __restrict__ attS2, const void* __restrict__ attD2,
        float* __restrict__ h2, float* __restrict__ a2s, float* __restrict__ a2d,
        const int* __restrict__ flag, int N){
    int t = threadIdx.x;
    int lane = t & 63, wv = t >> 6;
    int n = blockIdx.x*4 + wv;
    if (n >= N) return;
    int beg = rowptr[n];
    int deg = rowptr[n+1] - beg;

    int cl = lane & 31;          // channel group: channels cl*8..cl*8+7
    int hb = cl >> 2;            // head of this group
    int half = lane >> 5;        // edge parity
    float adb = a_d[n*8 + hb];

    float acc[8];
    #pragma unroll
    for (int j = 0; j < 8; j++) acc[j] = 0.f;
    float z = 0.f;

    int e = half;
    for (; e + 6 < deg; e += 8){
        int s0 = srcs[beg + e];
        int s1 = srcs[beg + e + 2];
        int s2 = srcs[beg + e + 4];
        int s3 = srcs[beg + e + 6];
        float w0 = __expf(fminf(lrelu(a_s[s0*8 + hb] + adb), 80.f));
        float w1 = __expf(fminf(lrelu(a_s[s1*8 + hb] + adb), 80.f));
        float w2 = __expf(fminf(lrelu(a_s[s2*8 + hb] + adb), 80.f));
        float w3 = __expf(fminf(lrelu(a_s[s3*8 + hb] + adb), 80.f));
        bf16x8 v0 = *(const bf16x8*)&h1[(size_t)s0*256 + cl*8];
        bf16x8 v1 = *(const bf16x8*)&h1[(size_t)s1*256 + cl*8];
        bf16x8 v2 = *(const bf16x8*)&h1[(size_t)s2*256 + cl*8];
        bf16x8 v3 = *(const bf16x8*)&h1[(size_t)s3*256 + cl*8];
        z += (w0 + w1) + (w2 + w3);
        #pragma unroll
        for (int j = 0; j < 8; j++) acc[j] += w0 * bfbits(v0[j]);
        #pragma unroll
        for (int j = 0; j < 8; j++) acc[j] += w1 * bfbits(v1[j]);
        #pragma unroll
        for (int j = 0; j < 8; j++) acc[j] += w2 * bfbits(v2[j]);
        #pragma unroll
        for (int j = 0; j < 8; j++) acc[j] += w3 * bfbits(v3[j]);
    }
    for (; e < deg; e += 2){
        int s = srcs[beg + e];
        float w = __expf(fminf(lrelu(a_s[s*8 + hb] + adb), 80.f));
        bf16x8 hv = *(const bf16x8*)&h1[(size_t)s*256 + cl*8];
        z += w;
        #pragma unroll
        for (int j = 0; j < 8; j++) acc[j] += w * bfbits(hv[j]);
    }
    #pragma unroll
    for (int j = 0; j < 8; j++) acc[j] += __shfl_xor(acc[j], 32);
    z += __shfl_xor(z, 32);
    float rz = 1.f / (z + 1e-16f);

    int isb = *flag;
    bf16x8 bv = load8(b1, cl*8, isb);
    float xv[8];
    #pragma unroll
    for (int j = 0; j < 8; j++){
        float v = acc[j] * rz + bfbits(bv[j]);
        xv[j] = v > 0.f ? v : expm1f(v);
    }
    // ---- fused layer-2 GEMV: h2[n][o] = sum_c xv[c]*W2[c][o]; lane covers o = half*4..half*4+3
    float p[4] = {0.f, 0.f, 0.f, 0.f};
    #pragma unroll
    for (int j = 0; j < 8; j++){
        int c = cl*8 + j;
        float wr[4];
        if (isb){
            s16x4 q = *(const s16x4*)((const bf16*)W2 + c*8 + half*4);
            #pragma unroll
            for (int o = 0; o < 4; o++) wr[o] = bfbits(q[o]);
        } else {
            f32x4 q = *(const f32x4*)((const float*)W2 + c*8 + half*4);
            #pragma unroll
            for (int o = 0; o < 4; o++) wr[o] = q[o];
        }
        #pragma unroll
        for (int o = 0; o < 4; o++) p[o] += xv[j] * wr[o];
    }
    #pragma unroll
    for (int o = 0; o < 4; o++){
        p[o] += __shfl_xor(p[o], 1);
        p[o] += __shfl_xor(p[o], 2);
        p[o] += __shfl_xor(p[o], 4);
        p[o] += __shfl_xor(p[o], 8);
        p[o] += __shfl_xor(p[o], 16);
    }
    float as2 = 0.f, ad2 = 0.f;
    #pragma unroll
    for (int o = 0; o < 4; o++){
        as2 += p[o] * cvtf(attS2, half*4 + o, isb);
        ad2 += p[o] * cvtf(attD2, half*4 + o, isb);
    }
    as2 += __shfl_xor(as2, 32);
    ad2 += __shfl_xor(ad2, 32);
    if (lane == 0){ a2s[n] = as2; a2d[n] = ad2; }
    if ((lane & 31) == 0)
        *(f32x4*)&h2[(size_t)n*8 + half*4] = (f32x4){p[0], p[1], p[2], p[3]};
}

// ---------------- layer-2: single-sweep aggregate + bias + log_softmax ----------------
__global__ __launch_bounds__(256) void k_edge2(const int* __restrict__ rowptr,
        const int* __restrict__ srcs, const float* __restrict__ a2s,
        const float* __restrict__ a2d, const float* __restrict__ h2,
        const void* __restrict__ b2, void* __restrict__ outv,
        const int* __restrict__ flag, int N){
    int t = threadIdx.x;
    int lane = t & 63, wv = t >> 6;
    int n = blockIdx.x*4 + wv;
    if (n >= N) return;
    int beg = rowptr[n];
    int deg = rowptr[n+1] - beg;
    float adh = a2d[n];
    int ep = lane >> 3, c = lane & 7;
    float acc = 0.f, z = 0.f;
    for (int e = ep; e < deg; e += 8){
        int s = srcs[beg + e];
        float w = __expf(fminf(lrelu(a2s[s] + adh), 80.f));
        z += w;
        acc += w * h2[(size_t)s*8 + c];
    }
    acc += __shfl_xor(acc, 8);
    acc += __shfl_xor(acc, 16);
    acc += __shfl_xor(acc, 32);
    z += __shfl_xor(z, 8);
    z += __shfl_xor(z, 16);
    z += __shfl_xor(z, 32);
    int isb = *flag;
    float val = acc / (z + 1e-16f) + cvtf(b2, c, isb);
    float mx = val;
    mx = fmaxf(mx, __shfl_xor(mx, 1));
    mx = fmaxf(mx, __shfl_xor(mx, 2));
    mx = fmaxf(mx, __shfl_xor(mx, 4));
    float se = __expf(val - mx);
    se += __shfl_xor(se, 1); se += __shfl_xor(se, 2); se += __shfl_xor(se, 4);
    float r = val - mx - __logf(se);
    if (lane < 8){
        if (isb) ((bf16*)outv)[(size_t)n*8 + c] = f2bf(r);
        else     ((float*)outv)[(size_t)n*8 + c] = r;
    }
}

extern "C" void kernel_launch(void* const* d_in, const int* in_sizes, int n_in,
                              void* d_out, int out_size, void* d_ws, size_t ws_size,
                              hipStream_t stream) {
    const int* ei = (const int*)d_in[2];
    const int N = in_sizes[0] / 128;
    const int E = in_sizes[2] / 2;
    const int ET = E + N;
    const int NBUK = (N + 255) >> 8;

    char* p = (char*)d_ws;
    auto alloc = [&](size_t bytes) -> void* {
        char* r = p;
        p += (bytes + 255) & ~(size_t)255;
        return (void*)r;
    };
    int*   flag      = (int*)  alloc(256);
    int*   bucketCnt = (int*)  alloc((size_t)NBUK*4);
    int*   bucketPtr = (int*)  alloc((size_t)(NBUK+1)*4);
    int*   bucketCur = (int*)  alloc((size_t)NBUK*16*4);   // strided: 1 int per 64B
    int*   rowptr    = (int*)  alloc((size_t)(N+1)*4);
    int*   srcs      = (int*)  alloc((size_t)ET*4);
    int*   pk        = (int*)  alloc((size_t)E*4);
    bf16*  Bp        = (bf16*) alloc((size_t)192*256*2);
    bf16*  emb       = (bf16*) alloc((size_t)N*64*2);
    bf16*  h1        = (bf16*) alloc((size_t)N*256*2);
    float* a_s       = (float*)alloc((size_t)N*8*4);
    float* a_d       = (float*)alloc((size_t)N*8*4);
    float* h2        = (float*)alloc((size_t)N*8*4);
    float* a2s       = (float*)alloc((size_t)N*4);
    float* a2d      = (float*)alloc((size_t)N*4);

    hipMemsetAsync(bucketCnt, 0, (size_t)NBUK*4, stream);
    k_init<<<256, 256, 0, stream>>>((const unsigned short*)d_in[0], flag,
            ei + E, bucketCnt, E, NBUK, 256);
    {
        int nEmb  = (N + 127)/128;
        int nPack = (16*6*64*8)/256;
        k_prep<<<nEmb + nPack, 256, 0, stream>>>(d_in[1], d_in[3], d_in[4],
                d_in[5], emb, Bp, flag, N, nEmb);
    }
    k_bscan<<<1, 256, 0, stream>>>(bucketCnt, bucketPtr, bucketCur, rowptr, N, E, NBUK);
    {
        int nG = (N + 63)/64;
        int nScat = (E + CHK - 1)/CHK;
        k_sg<<<nScat + nG, 256, 0, stream>>>(ei, bucketCur, pk,
                d_in[0], emb, Bp, d_in[6], d_in[7], h1, a_s, a_d, flag, N, E, nScat, NBUK);
    }
    k_fine<<<NBUK, 256, 0, stream>>>(bucketPtr, pk, rowptr, srcs, N);
    k_edge1<<<(N + 3)/4, 256, 0, stream>>>(rowptr, srcs, a_s, a_d, h1, d_in[8],
            d_in[9], d_in[10], d_in[11], h2, a2s, a2d, flag, N);
    k_edge2<<<(N + 3)/4, 256, 0, stream>>>(rowptr, srcs, a2s, a2d, h2, d_in[12], d_out, flag, N);
}

// Round 6
// 302.137 us; speedup vs baseline: 1.0467x; 1.0382x over previous
//
#include <hip/hip_runtime.h>
#include <hip/hip_bf16.h>

typedef __hip_bfloat16 bf16;
typedef short bf16x8 __attribute__((ext_vector_type(8)));
typedef float f32x4  __attribute__((ext_vector_type(4)));

#define CHK 2048

__device__ __forceinline__ float bf2f(bf16 v){ return __bfloat162float(v); }
__device__ __forceinline__ bf16  f2bf(float f){ return __float2bfloat16(f); }
__device__ __forceinline__ float lrelu(float a){ return a > 0.f ? a : 0.2f*a; }
__device__ __forceinline__ float bfbits(short s){
    union{unsigned u; float f;} cv; cv.u = ((unsigned)(unsigned short)s) << 16; return cv.f;
}
__device__ __forceinline__ short bf16s(float f){ bf16 q = f2bf(f); return *(short*)&q; }
// polymorphic scalar reads (isb wave-uniform)
__device__ __forceinline__ float cvtf(const void* p, int i, int isb){
    return isb ? bf2f(((const bf16*)p)[i]) : ((const float*)p)[i];
}
__device__ __forceinline__ short cvts(const void* p, int i, int isb){
    return isb ? ((const short*)p)[i] : bf16s(((const float*)p)[i]);
}
// load 8 contiguous values as bf16x8 from either bf16 or f32 source
__device__ __forceinline__ bf16x8 load8(const void* base, size_t off, int isb){
    if (isb) return *(const bf16x8*)((const bf16*)base + off);
    const float* f = (const float*)base + off;
    f32x4 v0 = *(const f32x4*)f;
    f32x4 v1 = *(const f32x4*)(f + 4);
    short r[8];
    #pragma unroll
    for (int j = 0; j < 4; j++) r[j]   = bf16s(v0[j]);
    #pragma unroll
    for (int j = 0; j < 4; j++) r[4+j] = bf16s(v1[j]);
    return *(const bf16x8*)r;
}

// ---------------- init: dtype detect (block 0) + coarse bucket histogram of dst ----------------
__global__ __launch_bounds__(256) void k_init(const unsigned short* __restrict__ raw,
        int* __restrict__ flag, const int* __restrict__ dst,
        int* __restrict__ bucketCnt, int E, int NBUK, int nBlk){
    __shared__ int h[256];
    int t = threadIdx.x;
    if (blockIdx.x == 0){
        unsigned short w = raw[2*t];
        int e = (w >> 7) & 0xFF;
        int ok = (e >= 90 && e <= 140) ? 1 : 0;
        __shared__ int cnt;
        if (t == 0) cnt = 0;
        __syncthreads();
        atomicAdd(&cnt, ok);
        __syncthreads();
        if (t == 0) *flag = (cnt >= 192) ? 1 : 0;  // 1 = bf16, 0 = f32
    }
    h[t] = 0;
    __syncthreads();
    for (int i = blockIdx.x*256 + t; i < E; i += nBlk*256)
        atomicAdd(&h[((unsigned)dst[i]) >> 8], 1);
    __syncthreads();
    if (t < NBUK && h[t]) atomicAdd(&bucketCnt[t], h[t]);
}

// ---------------- prep: emb (blocks<nEmb, 4 tiles each) | pack W1/W2 ----------------
__global__ __launch_bounds__(256) void k_prep(const void* __restrict__ low,
        const void* __restrict__ Wemb, const void* __restrict__ bemb,
        const void* __restrict__ W1, const void* __restrict__ W2,
        bf16* __restrict__ emb, bf16* __restrict__ Bp, bf16* __restrict__ Bp2,
        const int* __restrict__ flag, int N, int nEmb){
    __shared__ float wem[2048 + 64];
    __shared__ short lows[1024];
    int t = threadIdx.x;
    int b = blockIdx.x;
    int isb = *flag;
    if (b >= nEmb){
        // pack role
        int i = (b - nEmb)*256 + t;
        if (i < 16*6*64*8){
            int j = i & 7;
            int lane = (i >> 3) & 63;
            int r = i >> 9;
            int kt = r % 6, nt = r / 6;
            int k = kt*32 + (lane >> 4)*8 + j;
            int n = nt*16 + (lane & 15);
            *(short*)&Bp[i] = cvts(W1, k*256 + n, isb);
        } else {
            int i2 = i - 16*6*64*8;
            if (i2 >= 8*64*8) return;
            int j = i2 & 7;
            int lane = (i2 >> 3) & 63;
            int kt = i2 >> 9;
            int k = kt*32 + (lane >> 4)*8 + j;
            int n = lane & 15;
            *(short*)&Bp2[i2] = (n < 8) ? cvts(W2, k*8 + n, isb) : (short)0;
        }
        return;
    }
    // embedding role: four 32-node tiles sharing one W_emb load
    for (int i = t; i < 2048; i += 256) wem[i] = cvtf(Wemb, i, isb);
    if (t < 64) wem[2048 + t] = cvtf(bemb, t, isb);
    int nl = t >> 3, j8 = (t & 7) * 8;
    for (int tile = 0; tile < 4; tile++){
        int nb0 = b*128 + tile*32;
        __syncthreads();   // wem ready (tile 0) / previous tile compute done
        int lim = (N - nb0) * 32;
        if (lim > 1024) lim = 1024;
        if (lim < 0) lim = 0;
        for (int i = t; i < 1024; i += 256)
            lows[i] = (i < lim) ? cvts(low, nb0*32 + i, isb) : (short)0;
        __syncthreads();
        float acc[8];
        #pragma unroll
        for (int j = 0; j < 8; j++) acc[j] = wem[2048 + j8 + j];
        for (int k = 0; k < 32; k++){
            float lv = bfbits(lows[nl*32 + k]);
            f32x4 w0 = *(const f32x4*)&wem[k*64 + j8];
            f32x4 w1 = *(const f32x4*)&wem[k*64 + j8 + 4];
            #pragma unroll
            for (int j = 0; j < 4; j++) acc[j]   += lv * w0[j];
            #pragma unroll
            for (int j = 0; j < 4; j++) acc[4+j] += lv * w1[j];
        }
        int n = nb0 + nl;
        if (n < N){
            short ov[8];
            #pragma unroll
            for (int j = 0; j < 8; j++){
                float v = acc[j];
                ov[j] = bf16s(v > 0.f ? v : expm1f(v));
            }
            *(bf16x8*)&emb[(size_t)n*64 + j8] = *(const bf16x8*)ov;
        }
    }
}

// ---------------- single-block scan of coarse bucket counts ----------------
__global__ __launch_bounds__(256) void k_bscan(const int* __restrict__ bucketCnt,
        int* __restrict__ bucketPtr, int* __restrict__ bucketCur,
        int* __restrict__ rowptr, int N, int E, int NBUK){
    __shared__ int sd[256];
    int t = threadIdx.x;
    int v = (t < NBUK) ? bucketCnt[t] : 0;
    sd[t] = v;
    __syncthreads();
    #pragma unroll
    for (int off = 1; off < 256; off <<= 1){
        int a = (t >= off) ? sd[t - off] : 0;
        __syncthreads();
        sd[t] += a;
        __syncthreads();
    }
    int excl = sd[t] - v;
    if (t < NBUK){ bucketPtr[t] = excl; bucketCur[t*16] = excl; }  // cur strided: 1 int / 64B
    if (t == 0){ bucketPtr[NBUK] = sd[255]; rowptr[N] = E + N; }
}

// ---------------- merged: bucketed edge scatter (blocks < nScat) | GEMM1 (LDS-staged A) ----------------
__global__ __launch_bounds__(256) void k_sg(
        const int* __restrict__ ei, int* __restrict__ bucketCur, int* __restrict__ pk,
        const void* __restrict__ highv, const bf16* __restrict__ emb,
        const bf16* __restrict__ Bp, const void* __restrict__ attS,
        const void* __restrict__ attD, bf16* __restrict__ h1,
        float* __restrict__ a_s, float* __restrict__ a_d,
        const int* __restrict__ flag, int N, int E, int nScat, int NBUK){
    const int RS = 260;
    __shared__ union SM {
        struct { short Ah[64*128]; short Ae[64*64]; } a;                        // 24576B
        struct { float eb[16*260 + 16]; } g;                                     // 16704B (aliases Ah)
        struct { unsigned short dstS[CHK]; int hist[4][256]; int cur[4][256]; } s;// 12288B
    } sm;
    __shared__ float att[512];
    int t = threadIdx.x;
    if ((int)blockIdx.x < nScat){
        // ---- bucketed scatter role: pack (dstLow<<24 | src) grouped by dst>>8 ----
        int base = blockIdx.x * CHK;
        int cnt = E - base; if (cnt > CHK) cnt = CHK;
        int wv = t >> 6, lane = t & 63;
        #pragma unroll
        for (int w = 0; w < 4; w++) sm.s.hist[w][t] = 0;
        __syncthreads();
        const int* dstp = ei + E + base;
        const int* srcp = ei + base;
        int per = (cnt + 3) >> 2;
        int wb = wv*per, we = wb + per;
        if (we > cnt) we = cnt;
        if (wb > cnt) wb = cnt;
        for (int i = wb + lane; i < we; i += 64){
            int d = dstp[i];
            sm.s.dstS[i] = (unsigned short)d;
            atomicAdd(&sm.s.hist[wv][((unsigned)d) >> 8], 1);   // wave-private
        }
        __syncthreads();
        if (t < NBUK){
            int h0 = sm.s.hist[0][t], h1v = sm.s.hist[1][t];
            int h2 = sm.s.hist[2][t], h3 = sm.s.hist[3][t];
            int c = h0 + h1v + h2 + h3;
            int bs = c ? atomicAdd(&bucketCur[t*16], c) : 0;
            sm.s.cur[0][t] = bs;
            sm.s.cur[1][t] = bs + h0;
            sm.s.cur[2][t] = bs + h0 + h1v;
            sm.s.cur[3][t] = bs + h0 + h1v + h2;
        }
        __syncthreads();
        for (int i = wb + lane; i < we; i += 64){
            int d = sm.s.dstS[i];
            int pos = atomicAdd(&sm.s.cur[wv][d >> 8], 1);      // wave-private
            pk[pos] = ((d & 255) << 24) | srcp[i];
        }
        return;
    }
    // ---- GEMM1 role ----
    int isb = *flag;
    att[t] = cvtf(attS, t, isb);
    att[256 + t] = cvtf(attD, t, isb);
    int w = t >> 6, lane = t & 63;
    int m_lo = lane & 15, quad = lane >> 4;
    int m0 = (blockIdx.x - nScat) * 64;

    // ---- stage A (high 64x128 + emb 64x64) into XOR-swizzled LDS, coalesced ----
    #pragma unroll
    for (int ii = 0; ii < 4; ii++){
        int id = t + ii*256;            // 0..1023
        int r = id >> 4, c = id & 15;
        int gr = m0 + r; if (gr >= N) gr = N-1;
        bf16x8 v = load8(highv, (size_t)gr*128 + c*8, isb);
        *(bf16x8*)&sm.a.Ah[r*128 + ((c ^ (r & 7)) << 3)] = v;
    }
    #pragma unroll
    for (int ii = 0; ii < 2; ii++){
        int id = t + ii*256;            // 0..511
        int r = id >> 3, c = id & 7;
        int gr = m0 + r; if (gr >= N) gr = N-1;
        bf16x8 v = *(const bf16x8*)&emb[(size_t)gr*64 + c*8];
        *(bf16x8*)&sm.a.Ae[r*64 + ((c ^ (r & 7)) << 3)] = v;
    }
    __syncthreads();

    f32x4 acc[4][4];
    #pragma unroll
    for (int rt = 0; rt < 4; rt++)
        #pragma unroll
        for (int ct = 0; ct < 4; ct++) acc[rt][ct] = (f32x4){0.f,0.f,0.f,0.f};

    int sw = m_lo & 7;   // row-XOR for fragment reads
    #pragma unroll 2
    for (int kt = 0; kt < 6; kt++){
        bf16x8 a[4], b[4];
        if (kt < 4){
            int ch = (kt*4 + quad) ^ sw;
            #pragma unroll
            for (int rt = 0; rt < 4; rt++)
                a[rt] = *(const bf16x8*)&sm.a.Ah[(rt*16 + m_lo)*128 + (ch << 3)];
        } else {
            int ch = ((kt-4)*4 + quad) ^ sw;
            #pragma unroll
            for (int rt = 0; rt < 4; rt++)
                a[rt] = *(const bf16x8*)&sm.a.Ae[(rt*16 + m_lo)*64 + (ch << 3)];
        }
        #pragma unroll
        for (int ct = 0; ct < 4; ct++)
            b[ct] = *(const bf16x8*)&Bp[(size_t)(((w*4 + ct)*6 + kt)*64 + lane)*8];
        #pragma unroll
        for (int rt = 0; rt < 4; rt++)
            #pragma unroll
            for (int ct = 0; ct < 4; ct++)
                acc[rt][ct] = __builtin_amdgcn_mfma_f32_16x16x32_bf16(a[rt], b[ct], acc[rt][ct], 0, 0, 0);
    }

    float* eb = sm.g.eb;   // aliases Ah — safe: barriers below separate all uses
    #pragma unroll 1
    for (int rt = 0; rt < 4; rt++){
        __syncthreads();
        #pragma unroll
        for (int ct = 0; ct < 4; ct++)
            #pragma unroll
            for (int reg = 0; reg < 4; reg++)
                eb[(quad*4 + reg)*RS + w*64 + ct*16 + m_lo] = acc[rt][ct][reg];
        __syncthreads();
        int r = t >> 4, cb = t & 15;
        int c0 = cb * 16;
        int m = m0 + rt*16 + r;
        f32x4 v[4];
        #pragma unroll
        for (int p = 0; p < 4; p++) v[p] = *(const f32x4*)&eb[r*RS + c0 + p*4];
        float ps = 0.f, pd = 0.f;
        #pragma unroll
        for (int p = 0; p < 4; p++)
            #pragma unroll
            for (int j = 0; j < 4; j++){
                ps += v[p][j] * att[c0 + p*4 + j];
                pd += v[p][j] * att[256 + c0 + p*4 + j];
            }
        if (m < N){
            short ov[16];
            #pragma unroll
            for (int p = 0; p < 4; p++)
                #pragma unroll
                for (int j = 0; j < 4; j++) ov[p*4+j] = bf16s(v[p][j]);
            *(bf16x8*)&h1[(size_t)m*256 + c0]     = *(const bf16x8*)&ov[0];
            *(bf16x8*)&h1[(size_t)m*256 + c0 + 8] = *(const bf16x8*)&ov[8];
        }
        ps += __shfl_xor(ps, 1);
        pd += __shfl_xor(pd, 1);
        if (((t & 1) == 0) && m < N){
            int hd = cb >> 1;
            a_s[m*8 + hd] = ps;
            a_d[m*8 + hd] = pd;
        }
    }
}

// ---------------- fine pass: per-bucket dst counts (wave-private), scan, self-loops, final scatter ----------------
__global__ __launch_bounds__(256) void k_fine(const int* __restrict__ bucketPtr,
        const int* __restrict__ pk, int* __restrict__ rowptr, int* __restrict__ srcs,
        int N){
    __shared__ int hist[4][256];
    __shared__ int cur[4][256];
    __shared__ int sd[256];
    int t = threadIdx.x;
    int wv = t >> 6, lane = t & 63;
    int b = blockIdx.x;
    int d0 = b << 8;
    int nd = N - d0; if (nd > 256) nd = 256; if (nd < 0) nd = 0;
    int ebeg = bucketPtr[b], eend = bucketPtr[b+1];
    int tot = eend - ebeg;
    int per = (tot + 3) >> 2;
    int wb = wv*per, we = wb + per;
    if (we > tot) we = tot;
    if (wb > tot) wb = tot;
    #pragma unroll
    for (int w = 0; w < 4; w++) hist[w][t] = 0;
    __syncthreads();
    for (int i = wb + lane; i < we; i += 64)
        atomicAdd(&hist[wv][((unsigned)pk[ebeg + i]) >> 24], 1);   // wave-private
    __syncthreads();
    int h0 = hist[0][t], h1 = hist[1][t], h2 = hist[2][t], h3 = hist[3][t];
    int selfc = (t < nd) ? 1 : 0;
    int v = selfc + h0 + h1 + h2 + h3;
    sd[t] = v;
    __syncthreads();
    #pragma unroll
    for (int off = 1; off < 256; off <<= 1){
        int a = (t >= off) ? sd[t - off] : 0;
        __syncthreads();
        sd[t] += a;
        __syncthreads();
    }
    int r = ebeg + d0 + sd[t] - v;   // prior self-loops = d0 (all earlier buckets full)
    if (t < nd){
        rowptr[d0 + t] = r;
        srcs[r] = d0 + t;            // self-loop at segment head
    }
    int c0 = r + selfc;
    cur[0][t] = c0;
    cur[1][t] = c0 + h0;
    cur[2][t] = c0 + h0 + h1;
    cur[3][t] = c0 + h0 + h1 + h2;
    __syncthreads();
    for (int i = wb + lane; i < we; i += 64){
        int p = pk[ebeg + i];
        int pos = atomicAdd(&cur[wv][((unsigned)p) >> 24], 1);     // wave-private
        srcs[pos] = p & 0xFFFFFF;
    }
}

// ---------------- layer-1: single-sweep unnormalized softmax aggregate + elu + bias (6-deep MLP) ----------------
__global__ __launch_bounds__(256) void k_edge1(const int* __restrict__ rowptr,
        const int* __restrict__ srcs, const float* __restrict__ a_s,
        const float* __restrict__ a_d, const bf16* __restrict__ h1,
        const void* __restrict__ b1, bf16* __restrict__ x2,
        const int* __restrict__ flag, int N){
    int t = threadIdx.x;
    int lane = t & 63, wv = t >> 6;
    int n = blockIdx.x*4 + wv;
    if (n >= N) return;
    int beg = rowptr[n];
    int deg = rowptr[n+1] - beg;

    int cl = lane & 31;          // channel group: channels cl*8..cl*8+7
    int hb = cl >> 2;            // head of this group
    int half = lane >> 5;        // edge parity
    float adb = a_d[n*8 + hb];

    float acc[8];
    #pragma unroll
    for (int j = 0; j < 8; j++) acc[j] = 0.f;
    float z = 0.f;

    int e = half;
    // main: 12 edges per iteration, 6 gathers in flight per lane
    for (; e + 10 < deg; e += 12){
        int s[6];
        #pragma unroll
        for (int q = 0; q < 6; q++) s[q] = srcs[beg + e + 2*q];
        float w[6];
        #pragma unroll
        for (int q = 0; q < 6; q++)
            w[q] = __expf(fminf(lrelu(a_s[s[q]*8 + hb] + adb), 80.f));
        bf16x8 v[6];
        #pragma unroll
        for (int q = 0; q < 6; q++)
            v[q] = *(const bf16x8*)&h1[(size_t)s[q]*256 + cl*8];
        z += ((w[0] + w[1]) + (w[2] + w[3])) + (w[4] + w[5]);
        #pragma unroll
        for (int q = 0; q < 6; q++){
            #pragma unroll
            for (int j = 0; j < 8; j++) acc[j] += w[q] * bfbits(v[q][j]);
        }
    }
    // mid: 4 edges per iteration, 2 in flight
    for (; e + 2 < deg; e += 4){
        int s0 = srcs[beg + e];
        int s1 = srcs[beg + e + 2];
        float w0 = __expf(fminf(lrelu(a_s[s0*8 + hb] + adb), 80.f));
        float w1 = __expf(fminf(lrelu(a_s[s1*8 + hb] + adb), 80.f));
        bf16x8 v0 = *(const bf16x8*)&h1[(size_t)s0*256 + cl*8];
        bf16x8 v1 = *(const bf16x8*)&h1[(size_t)s1*256 + cl*8];
        z += w0 + w1;
        #pragma unroll
        for (int j = 0; j < 8; j++) acc[j] += w0 * bfbits(v0[j]);
        #pragma unroll
        for (int j = 0; j < 8; j++) acc[j] += w1 * bfbits(v1[j]);
    }
    for (; e < deg; e += 2){
        int s = srcs[beg + e];
        float w = __expf(fminf(lrelu(a_s[s*8 + hb] + adb), 80.f));
        bf16x8 hv = *(const bf16x8*)&h1[(size_t)s*256 + cl*8];
        z += w;
        #pragma unroll
        for (int j = 0; j < 8; j++) acc[j] += w * bfbits(hv[j]);
    }
    #pragma unroll
    for (int j = 0; j < 8; j++) acc[j] += __shfl_xor(acc[j], 32);
    z += __shfl_xor(z, 32);
    float rz = 1.f / (z + 1e-16f);

    if (half == 0){
        int isb = *flag;
        bf16x8 bv = load8(b1, cl*8, isb);
        short ov[8];
        #pragma unroll
        for (int j = 0; j < 8; j++){
            float v = acc[j] * rz + bfbits(bv[j]);
            ov[j] = bf16s(v > 0.f ? v : expm1f(v));
        }
        *(bf16x8*)&x2[(size_t)n*256 + cl*8] = *(const bf16x8*)ov;
    }
}

// ---------------- GEMM2 (MFMA) + attention scalars layer 2 ----------------
__global__ __launch_bounds__(256) void k_gemm2(const bf16* __restrict__ x2,
        const bf16* __restrict__ Bp2, const void* __restrict__ attS,
        const void* __restrict__ attD, float* __restrict__ h2,
        float* __restrict__ a2s, float* __restrict__ a2d,
        const int* __restrict__ flag, int N){
    int t = threadIdx.x;
    int isb = *flag;
    int w = t >> 6, lane = t & 63;
    int m_lo = lane & 15, quad = lane >> 4;
    int m0 = blockIdx.x*64 + w*16;
    int mr = m0 + m_lo; if (mr >= N) mr = N-1;
    f32x4 acc = (f32x4){0.f,0.f,0.f,0.f};
    #pragma unroll
    for (int kt = 0; kt < 8; kt++){
        bf16x8 a = *(const bf16x8*)&x2[(size_t)mr*256 + kt*32 + quad*8];
        bf16x8 b = *(const bf16x8*)&Bp2[(size_t)(kt*64 + lane)*8];
        acc = __builtin_amdgcn_mfma_f32_16x16x32_bf16(a, b, acc, 0, 0, 0);
    }
    float s2 = (m_lo < 8) ? cvtf(attS, m_lo, isb) : 0.f;
    float d2 = (m_lo < 8) ? cvtf(attD, m_lo, isb) : 0.f;
    #pragma unroll
    for (int reg = 0; reg < 4; reg++){
        int m = m0 + quad*4 + reg;
        float val = acc[reg];
        float ps = val * s2, pd = val * d2;
        ps += __shfl_xor(ps, 1); ps += __shfl_xor(ps, 2);
        ps += __shfl_xor(ps, 4); ps += __shfl_xor(ps, 8);
        pd += __shfl_xor(pd, 1); pd += __shfl_xor(pd, 2);
        pd += __shfl_xor(pd, 4); pd += __shfl_xor(pd, 8);
        if (m < N){
            if (m_lo < 8) h2[(size_t)m*8 + m_lo] = val;
            if (m_lo == 0){ a2s[m] = ps; a2d[m] = pd; }
        }
    }
}

// ---------------- layer-2: single-sweep aggregate + bias + log_softmax (2-deep MLP) ----------------
__global__ __launch_bounds__(256) void k_edge2(const int* __restrict__ rowptr,
        const int* __restrict__ srcs, const float* __restrict__ a2s,
        const float* __restrict__ a2d, const float* __restrict__ h2,
        const void* __restrict__ b2, void* __restrict__ outv,
        const int* __restrict__ flag, int N){
    int t = threadIdx.x;
    int lane = t & 63, wv = t >> 6;
    int n = blockIdx.x*4 + wv;
    if (n >= N) return;
    int beg = rowptr[n];
    int deg = rowptr[n+1] - beg;
    float adh = a2d[n];
    int ep = lane >> 3, c = lane & 7;
    float acc = 0.f, z = 0.f;
    int e = ep;
    for (; e + 8 < deg; e += 16){
        int s0 = srcs[beg + e];
        int s1 = srcs[beg + e + 8];
        float w0 = __expf(fminf(lrelu(a2s[s0] + adh), 80.f));
        float w1 = __expf(fminf(lrelu(a2s[s1] + adh), 80.f));
        float g0 = h2[(size_t)s0*8 + c];
        float g1 = h2[(size_t)s1*8 + c];
        z += w0 + w1;
        acc += w0 * g0 + w1 * g1;
    }
    for (; e < deg; e += 8){
        int s = srcs[beg + e];
        float w = __expf(fminf(lrelu(a2s[s] + adh), 80.f));
        z += w;
        acc += w * h2[(size_t)s*8 + c];
    }
    acc += __shfl_xor(acc, 8);
    acc += __shfl_xor(acc, 16);
    acc += __shfl_xor(acc, 32);
    z += __shfl_xor(z, 8);
    z += __shfl_xor(z, 16);
    z += __shfl_xor(z, 32);
    int isb = *flag;
    float val = acc / (z + 1e-16f) + cvtf(b2, c, isb);
    float mx = val;
    mx = fmaxf(mx, __shfl_xor(mx, 1));
    mx = fmaxf(mx, __shfl_xor(mx, 2));
    mx = fmaxf(mx, __shfl_xor(mx, 4));
    float se = __expf(val - mx);
    se += __shfl_xor(se, 1); se += __shfl_xor(se, 2); se += __shfl_xor(se, 4);
    float r = val - mx - __logf(se);
    if (lane < 8){
        if (isb) ((bf16*)outv)[(size_t)n*8 + c] = f2bf(r);
        else     ((float*)outv)[(size_t)n*8 + c] = r;
    }
}

extern "C" void kernel_launch(void* const* d_in, const int* in_sizes, int n_in,
                              void* d_out, int out_size, void* d_ws, size_t ws_size,
                              hipStream_t stream) {
    const int* ei = (const int*)d_in[2];
    const int N = in_sizes[0] / 128;
    const int E = in_sizes[2] / 2;
    const int ET = E + N;
    const int NBUK = (N + 255) >> 8;

    char* p = (char*)d_ws;
    auto alloc = [&](size_t bytes) -> void* {
        char* r = p;
        p += (bytes + 255) & ~(size_t)255;
        return (void*)r;
    };
    int*   flag      = (int*)  alloc(256);
    int*   bucketCnt = (int*)  alloc((size_t)NBUK*4);
    int*   bucketPtr = (int*)  alloc((size_t)(NBUK+1)*4);
    int*   bucketCur = (int*)  alloc((size_t)NBUK*16*4);   // strided: 1 int per 64B
    int*   rowptr    = (int*)  alloc((size_t)(N+1)*4);
    int*   srcs      = (int*)  alloc((size_t)ET*4);
    int*   pk        = (int*)  alloc((size_t)E*4);
    bf16*  Bp        = (bf16*) alloc((size_t)192*256*2);
    bf16*  Bp2      = (bf16*) alloc((size_t)8*64*8*2);
    bf16*  emb       = (bf16*) alloc((size_t)N*64*2);
    bf16*  h1        = (bf16*) alloc((size_t)N*256*2);
    float* a_s       = (float*)alloc((size_t)N*8*4);
    float* a_d       = (float*)alloc((size_t)N*8*4);
    bf16*  x2        = (bf16*) alloc((size_t)N*256*2);
    float* h2        = (float*)alloc((size_t)N*8*4);
    float* a2s       = (float*)alloc((size_t)N*4);
    float* a2d       = (float*)alloc((size_t)N*4);

    hipMemsetAsync(bucketCnt, 0, (size_t)NBUK*4, stream);
    k_init<<<256, 256, 0, stream>>>((const unsigned short*)d_in[0], flag,
            ei + E, bucketCnt, E, NBUK, 256);
    {
        int nEmb  = (N + 127)/128;
        int nPack = (16*6*64*8 + 8*64*8 + 255)/256;
        k_prep<<<nEmb + nPack, 256, 0, stream>>>(d_in[1], d_in[3], d_in[4],
                d_in[5], d_in[9], emb, Bp, Bp2, flag, N, nEmb);
    }
    k_bscan<<<1, 256, 0, stream>>>(bucketCnt, bucketPtr, bucketCur, rowptr, N, E, NBUK);
    {
        int nG = (N + 63)/64;
        int nScat = (E + CHK - 1)/CHK;
        k_sg<<<nScat + nG, 256, 0, stream>>>(ei, bucketCur, pk,
                d_in[0], emb, Bp, d_in[6], d_in[7], h1, a_s, a_d, flag, N, E, nScat, NBUK);
    }
    k_fine<<<NBUK, 256, 0, stream>>>(bucketPtr, pk, rowptr, srcs, N);
    k_edge1<<<(N + 3)/4, 256, 0, stream>>>(rowptr, srcs, a_s, a_d, h1, d_in[8], x2, flag, N);
    k_gemm2<<<(N + 63)/64, 256, 0, stream>>>(x2, Bp2, d_in[10], d_in[11], h2, a2s, a2d, flag, N);
    k_edge2<<<(N + 3)/4, 256, 0, stream>>>(rowptr, srcs, a2s, a2d, h2, d_in[12], d_out, flag, N);
}

// Round 7
// 300.819 us; speedup vs baseline: 1.0512x; 1.0044x over previous
//
#include <hip/hip_runtime.h>
#include <hip/hip_bf16.h>

typedef __hip_bfloat16 bf16;
typedef short bf16x8 __attribute__((ext_vector_type(8)));
typedef float f32x4  __attribute__((ext_vector_type(4)));
typedef float f32x2  __attribute__((ext_vector_type(2)));
typedef int   i32x4  __attribute__((ext_vector_type(4)));

#define CHK 2048

__device__ __forceinline__ float bf2f(bf16 v){ return __bfloat162float(v); }
__device__ __forceinline__ bf16  f2bf(float f){ return __float2bfloat16(f); }
__device__ __forceinline__ float lrelu(float a){ return a > 0.f ? a : 0.2f*a; }
__device__ __forceinline__ float bfbits(short s){
    union{unsigned u; float f;} cv; cv.u = ((unsigned)(unsigned short)s) << 16; return cv.f;
}
__device__ __forceinline__ float fbits(int u){ union{int i; float f;} c; c.i = u; return c.f; }
__device__ __forceinline__ short bf16s(float f){ bf16 q = f2bf(f); return *(short*)&q; }
// polymorphic scalar reads (isb wave-uniform)
__device__ __forceinline__ float cvtf(const void* p, int i, int isb){
    return isb ? bf2f(((const bf16*)p)[i]) : ((const float*)p)[i];
}
__device__ __forceinline__ short cvts(const void* p, int i, int isb){
    return isb ? ((const short*)p)[i] : bf16s(((const float*)p)[i]);
}
// load 8 contiguous values as bf16x8 from either bf16 or f32 source
__device__ __forceinline__ bf16x8 load8(const void* base, size_t off, int isb){
    if (isb) return *(const bf16x8*)((const bf16*)base + off);
    const float* f = (const float*)base + off;
    f32x4 v0 = *(const f32x4*)f;
    f32x4 v1 = *(const f32x4*)(f + 4);
    short r[8];
    #pragma unroll
    for (int j = 0; j < 4; j++) r[j]   = bf16s(v0[j]);
    #pragma unroll
    for (int j = 0; j < 4; j++) r[4+j] = bf16s(v1[j]);
    return *(const bf16x8*)r;
}

// packed accumulate: acc2[k] holds channels {2k, 2k+1}; dword-wise bf16 unpack (1 op/ch)
__device__ __forceinline__ void acc8p(f32x2 acc2[4], float w, bf16x8 v){
    i32x4 iv = *(const i32x4*)&v;
    f32x2 w2 = {w, w};
    #pragma unroll
    for (int k = 0; k < 4; k++){
        int d = iv[k];
        f32x2 hv = {fbits(d << 16), fbits(d & 0xffff0000)};
        acc2[k] += w2 * hv;
    }
}

// ---------------- init: dtype detect (block 0) + coarse bucket histogram of dst ----------------
__global__ __launch_bounds__(256) void k_init(const unsigned short* __restrict__ raw,
        int* __restrict__ flag, const int* __restrict__ dst,
        int* __restrict__ bucketCnt, int E, int NBUK, int nBlk){
    __shared__ int h[256];
    int t = threadIdx.x;
    if (blockIdx.x == 0){
        unsigned short w = raw[2*t];
        int e = (w >> 7) & 0xFF;
        int ok = (e >= 90 && e <= 140) ? 1 : 0;
        __shared__ int cnt;
        if (t == 0) cnt = 0;
        __syncthreads();
        atomicAdd(&cnt, ok);
        __syncthreads();
        if (t == 0) *flag = (cnt >= 192) ? 1 : 0;  // 1 = bf16, 0 = f32
    }
    h[t] = 0;
    __syncthreads();
    for (int i = blockIdx.x*256 + t; i < E; i += nBlk*256)
        atomicAdd(&h[((unsigned)dst[i]) >> 8], 1);
    __syncthreads();
    if (t < NBUK && h[t]) atomicAdd(&bucketCnt[t], h[t]);
}

// ---------------- prep: emb (blocks<nEmb, 4 tiles each) | pack W1/W2 ----------------
__global__ __launch_bounds__(256) void k_prep(const void* __restrict__ low,
        const void* __restrict__ Wemb, const void* __restrict__ bemb,
        const void* __restrict__ W1, const void* __restrict__ W2,
        bf16* __restrict__ emb, bf16* __restrict__ Bp, bf16* __restrict__ Bp2,
        const int* __restrict__ flag, int N, int nEmb){
    __shared__ float wem[2048 + 64];
    __shared__ short lows[1024];
    int t = threadIdx.x;
    int b = blockIdx.x;
    int isb = *flag;
    if (b >= nEmb){
        // pack role
        int i = (b - nEmb)*256 + t;
        if (i < 16*6*64*8){
            int j = i & 7;
            int lane = (i >> 3) & 63;
            int r = i >> 9;
            int kt = r % 6, nt = r / 6;
            int k = kt*32 + (lane >> 4)*8 + j;
            int n = nt*16 + (lane & 15);
            *(short*)&Bp[i] = cvts(W1, k*256 + n, isb);
        } else {
            int i2 = i - 16*6*64*8;
            if (i2 >= 8*64*8) return;
            int j = i2 & 7;
            int lane = (i2 >> 3) & 63;
            int kt = i2 >> 9;
            int k = kt*32 + (lane >> 4)*8 + j;
            int n = lane & 15;
            *(short*)&Bp2[i2] = (n < 8) ? cvts(W2, k*8 + n, isb) : (short)0;
        }
        return;
    }
    // embedding role: four 32-node tiles sharing one W_emb load
    for (int i = t; i < 2048; i += 256) wem[i] = cvtf(Wemb, i, isb);
    if (t < 64) wem[2048 + t] = cvtf(bemb, t, isb);
    int nl = t >> 3, j8 = (t & 7) * 8;
    for (int tile = 0; tile < 4; tile++){
        int nb0 = b*128 + tile*32;
        __syncthreads();   // wem ready (tile 0) / previous tile compute done
        int lim = (N - nb0) * 32;
        if (lim > 1024) lim = 1024;
        if (lim < 0) lim = 0;
        for (int i = t; i < 1024; i += 256)
            lows[i] = (i < lim) ? cvts(low, nb0*32 + i, isb) : (short)0;
        __syncthreads();
        float acc[8];
        #pragma unroll
        for (int j = 0; j < 8; j++) acc[j] = wem[2048 + j8 + j];
        for (int k = 0; k < 32; k++){
            float lv = bfbits(lows[nl*32 + k]);
            f32x4 w0 = *(const f32x4*)&wem[k*64 + j8];
            f32x4 w1 = *(const f32x4*)&wem[k*64 + j8 + 4];
            #pragma unroll
            for (int j = 0; j < 4; j++) acc[j]   += lv * w0[j];
            #pragma unroll
            for (int j = 0; j < 4; j++) acc[4+j] += lv * w1[j];
        }
        int n = nb0 + nl;
        if (n < N){
            short ov[8];
            #pragma unroll
            for (int j = 0; j < 8; j++){
                float v = acc[j];
                ov[j] = bf16s(v > 0.f ? v : expm1f(v));
            }
            *(bf16x8*)&emb[(size_t)n*64 + j8] = *(const bf16x8*)ov;
        }
    }
}

// ---------------- single-block scan of coarse bucket counts ----------------
__global__ __launch_bounds__(256) void k_bscan(const int* __restrict__ bucketCnt,
        int* __restrict__ bucketPtr, int* __restrict__ bucketCur,
        int* __restrict__ rowptr, int N, int E, int NBUK){
    __shared__ int sd[256];
    int t = threadIdx.x;
    int v = (t < NBUK) ? bucketCnt[t] : 0;
    sd[t] = v;
    __syncthreads();
    #pragma unroll
    for (int off = 1; off < 256; off <<= 1){
        int a = (t >= off) ? sd[t - off] : 0;
        __syncthreads();
        sd[t] += a;
        __syncthreads();
    }
    int excl = sd[t] - v;
    if (t < NBUK){ bucketPtr[t] = excl; bucketCur[t*16] = excl; }  // cur strided: 1 int / 64B
    if (t == 0){ bucketPtr[NBUK] = sd[255]; rowptr[N] = E + N; }
}

// ---------------- merged: bucketed edge scatter (blocks < nScat) | GEMM1 (LDS-staged A) ----------------
__global__ __launch_bounds__(256) void k_sg(
        const int* __restrict__ ei, int* __restrict__ bucketCur, int* __restrict__ pk,
        const void* __restrict__ highv, const bf16* __restrict__ emb,
        const bf16* __restrict__ Bp, const void* __restrict__ attS,
        const void* __restrict__ attD, bf16* __restrict__ h1,
        float* __restrict__ a_s, float* __restrict__ a_d,
        const int* __restrict__ flag, int N, int E, int nScat, int NBUK){
    const int RS = 260;
    __shared__ union SM {
        struct { short Ah[64*128]; short Ae[64*64]; } a;                        // 24576B
        struct { float eb[16*260 + 16]; } g;                                     // 16704B (aliases Ah)
        struct { unsigned short dstS[CHK]; int hist[4][256]; int cur[4][256]; } s;// 12288B
    } sm;
    __shared__ float att[512];
    int t = threadIdx.x;
    if ((int)blockIdx.x < nScat){
        // ---- bucketed scatter role: pack (dstLow<<24 | src) grouped by dst>>8 ----
        int base = blockIdx.x * CHK;
        int cnt = E - base; if (cnt > CHK) cnt = CHK;
        int wv = t >> 6, lane = t & 63;
        #pragma unroll
        for (int w = 0; w < 4; w++) sm.s.hist[w][t] = 0;
        __syncthreads();
        const int* dstp = ei + E + base;
        const int* srcp = ei + base;
        int per = (cnt + 3) >> 2;
        int wb = wv*per, we = wb + per;
        if (we > cnt) we = cnt;
        if (wb > cnt) wb = cnt;
        for (int i = wb + lane; i < we; i += 64){
            int d = dstp[i];
            sm.s.dstS[i] = (unsigned short)d;
            atomicAdd(&sm.s.hist[wv][((unsigned)d) >> 8], 1);   // wave-private
        }
        __syncthreads();
        if (t < NBUK){
            int h0 = sm.s.hist[0][t], h1v = sm.s.hist[1][t];
            int h2 = sm.s.hist[2][t], h3 = sm.s.hist[3][t];
            int c = h0 + h1v + h2 + h3;
            int bs = c ? atomicAdd(&bucketCur[t*16], c) : 0;
            sm.s.cur[0][t] = bs;
            sm.s.cur[1][t] = bs + h0;
            sm.s.cur[2][t] = bs + h0 + h1v;
            sm.s.cur[3][t] = bs + h0 + h1v + h2;
        }
        __syncthreads();
        for (int i = wb + lane; i < we; i += 64){
            int d = sm.s.dstS[i];
            int pos = atomicAdd(&sm.s.cur[wv][d >> 8], 1);      // wave-private
            pk[pos] = ((d & 255) << 24) | srcp[i];
        }
        return;
    }
    // ---- GEMM1 role ----
    int isb = *flag;
    att[t] = cvtf(attS, t, isb);
    att[256 + t] = cvtf(attD, t, isb);
    int w = t >> 6, lane = t & 63;
    int m_lo = lane & 15, quad = lane >> 4;
    int m0 = (blockIdx.x - nScat) * 64;

    // ---- stage A (high 64x128 + emb 64x64) into XOR-swizzled LDS, coalesced ----
    #pragma unroll
    for (int ii = 0; ii < 4; ii++){
        int id = t + ii*256;            // 0..1023
        int r = id >> 4, c = id & 15;
        int gr = m0 + r; if (gr >= N) gr = N-1;
        bf16x8 v = load8(highv, (size_t)gr*128 + c*8, isb);
        *(bf16x8*)&sm.a.Ah[r*128 + ((c ^ (r & 7)) << 3)] = v;
    }
    #pragma unroll
    for (int ii = 0; ii < 2; ii++){
        int id = t + ii*256;            // 0..511
        int r = id >> 3, c = id & 7;
        int gr = m0 + r; if (gr >= N) gr = N-1;
        bf16x8 v = *(const bf16x8*)&emb[(size_t)gr*64 + c*8];
        *(bf16x8*)&sm.a.Ae[r*64 + ((c ^ (r & 7)) << 3)] = v;
    }
    __syncthreads();

    f32x4 acc[4][4];
    #pragma unroll
    for (int rt = 0; rt < 4; rt++)
        #pragma unroll
        for (int ct = 0; ct < 4; ct++) acc[rt][ct] = (f32x4){0.f,0.f,0.f,0.f};

    int sw = m_lo & 7;   // row-XOR for fragment reads
    #pragma unroll 2
    for (int kt = 0; kt < 6; kt++){
        bf16x8 a[4], b[4];
        if (kt < 4){
            int ch = (kt*4 + quad) ^ sw;
            #pragma unroll
            for (int rt = 0; rt < 4; rt++)
                a[rt] = *(const bf16x8*)&sm.a.Ah[(rt*16 + m_lo)*128 + (ch << 3)];
        } else {
            int ch = ((kt-4)*4 + quad) ^ sw;
            #pragma unroll
            for (int rt = 0; rt < 4; rt++)
                a[rt] = *(const bf16x8*)&sm.a.Ae[(rt*16 + m_lo)*64 + (ch << 3)];
        }
        #pragma unroll
        for (int ct = 0; ct < 4; ct++)
            b[ct] = *(const bf16x8*)&Bp[(size_t)(((w*4 + ct)*6 + kt)*64 + lane)*8];
        #pragma unroll
        for (int rt = 0; rt < 4; rt++)
            #pragma unroll
            for (int ct = 0; ct < 4; ct++)
                acc[rt][ct] = __builtin_amdgcn_mfma_f32_16x16x32_bf16(a[rt], b[ct], acc[rt][ct], 0, 0, 0);
    }

    float* eb = sm.g.eb;   // aliases Ah — safe: barriers below separate all uses
    #pragma unroll 1
    for (int rt = 0; rt < 4; rt++){
        __syncthreads();
        #pragma unroll
        for (int ct = 0; ct < 4; ct++)
            #pragma unroll
            for (int reg = 0; reg < 4; reg++)
                eb[(quad*4 + reg)*RS + w*64 + ct*16 + m_lo] = acc[rt][ct][reg];
        __syncthreads();
        int r = t >> 4, cb = t & 15;
        int c0 = cb * 16;
        int m = m0 + rt*16 + r;
        f32x4 v[4];
        #pragma unroll
        for (int p = 0; p < 4; p++) v[p] = *(const f32x4*)&eb[r*RS + c0 + p*4];
        float ps = 0.f, pd = 0.f;
        #pragma unroll
        for (int p = 0; p < 4; p++)
            #pragma unroll
            for (int j = 0; j < 4; j++){
                ps += v[p][j] * att[c0 + p*4 + j];
                pd += v[p][j] * att[256 + c0 + p*4 + j];
            }
        if (m < N){
            short ov[16];
            #pragma unroll
            for (int p = 0; p < 4; p++)
                #pragma unroll
                for (int j = 0; j < 4; j++) ov[p*4+j] = bf16s(v[p][j]);
            *(bf16x8*)&h1[(size_t)m*256 + c0]     = *(const bf16x8*)&ov[0];
            *(bf16x8*)&h1[(size_t)m*256 + c0 + 8] = *(const bf16x8*)&ov[8];
        }
        ps += __shfl_xor(ps, 1);
        pd += __shfl_xor(pd, 1);
        if (((t & 1) == 0) && m < N){
            int hd = cb >> 1;
            a_s[m*8 + hd] = ps;
            a_d[m*8 + hd] = pd;
        }
    }
}

// ---------------- fine pass: per-bucket dst counts (wave-private), scan, self-loops, final scatter ----------------
__global__ __launch_bounds__(256) void k_fine(const int* __restrict__ bucketPtr,
        const int* __restrict__ pk, int* __restrict__ rowptr, int* __restrict__ srcs,
        int N){
    __shared__ int hist[4][256];
    __shared__ int cur[4][256];
    __shared__ int sd[256];
    int t = threadIdx.x;
    int wv = t >> 6, lane = t & 63;
    int b = blockIdx.x;
    int d0 = b << 8;
    int nd = N - d0; if (nd > 256) nd = 256; if (nd < 0) nd = 0;
    int ebeg = bucketPtr[b], eend = bucketPtr[b+1];
    int tot = eend - ebeg;
    int per = (tot + 3) >> 2;
    int wb = wv*per, we = wb + per;
    if (we > tot) we = tot;
    if (wb > tot) wb = tot;
    #pragma unroll
    for (int w = 0; w < 4; w++) hist[w][t] = 0;
    __syncthreads();
    for (int i = wb + lane; i < we; i += 64)
        atomicAdd(&hist[wv][((unsigned)pk[ebeg + i]) >> 24], 1);   // wave-private
    __syncthreads();
    int h0 = hist[0][t], h1 = hist[1][t], h2 = hist[2][t], h3 = hist[3][t];
    int selfc = (t < nd) ? 1 : 0;
    int v = selfc + h0 + h1 + h2 + h3;
    sd[t] = v;
    __syncthreads();
    #pragma unroll
    for (int off = 1; off < 256; off <<= 1){
        int a = (t >= off) ? sd[t - off] : 0;
        __syncthreads();
        sd[t] += a;
        __syncthreads();
    }
    int r = ebeg + d0 + sd[t] - v;   // prior self-loops = d0 (all earlier buckets full)
    if (t < nd){
        rowptr[d0 + t] = r;
        srcs[r] = d0 + t;            // self-loop at segment head
    }
    int c0 = r + selfc;
    cur[0][t] = c0;
    cur[1][t] = c0 + h0;
    cur[2][t] = c0 + h0 + h1;
    cur[3][t] = c0 + h0 + h1 + h2;
    __syncthreads();
    for (int i = wb + lane; i < we; i += 64){
        int p = pk[ebeg + i];
        int pos = atomicAdd(&cur[wv][((unsigned)p) >> 24], 1);     // wave-private
        srcs[pos] = p & 0xFFFFFF;
    }
}

// ---------------- layer-1: single-sweep aggregate, packed f32x2 math + elu + bias ----------------
__global__ __launch_bounds__(256) void k_edge1(const int* __restrict__ rowptr,
        const int* __restrict__ srcs, const float* __restrict__ a_s,
        const float* __restrict__ a_d, const bf16* __restrict__ h1,
        const void* __restrict__ b1, bf16* __restrict__ x2,
        const int* __restrict__ flag, int N){
    int t = threadIdx.x;
    int lane = t & 63, wv = t >> 6;
    int n = blockIdx.x*4 + wv;
    if (n >= N) return;
    int beg = rowptr[n];
    int deg = rowptr[n+1] - beg;

    int cl = lane & 31;          // channel group: channels cl*8..cl*8+7
    int hb = cl >> 2;            // head of this group
    int half = lane >> 5;        // edge parity
    float adb = a_d[n*8 + hb];

    f32x2 acc2[4];
    #pragma unroll
    for (int k = 0; k < 4; k++) acc2[k] = (f32x2){0.f, 0.f};
    float z = 0.f;

    int e = half;
    for (; e + 6 < deg; e += 8){
        int s0 = srcs[beg + e];
        int s1 = srcs[beg + e + 2];
        int s2 = srcs[beg + e + 4];
        int s3 = srcs[beg + e + 6];
        float w0 = __expf(fminf(lrelu(a_s[s0*8 + hb] + adb), 80.f));
        float w1 = __expf(fminf(lrelu(a_s[s1*8 + hb] + adb), 80.f));
        float w2 = __expf(fminf(lrelu(a_s[s2*8 + hb] + adb), 80.f));
        float w3 = __expf(fminf(lrelu(a_s[s3*8 + hb] + adb), 80.f));
        bf16x8 v0 = *(const bf16x8*)&h1[(size_t)s0*256 + cl*8];
        bf16x8 v1 = *(const bf16x8*)&h1[(size_t)s1*256 + cl*8];
        bf16x8 v2 = *(const bf16x8*)&h1[(size_t)s2*256 + cl*8];
        bf16x8 v3 = *(const bf16x8*)&h1[(size_t)s3*256 + cl*8];
        z += (w0 + w1) + (w2 + w3);
        acc8p(acc2, w0, v0);
        acc8p(acc2, w1, v1);
        acc8p(acc2, w2, v2);
        acc8p(acc2, w3, v3);
    }
    for (; e < deg; e += 2){
        int s = srcs[beg + e];
        float w = __expf(fminf(lrelu(a_s[s*8 + hb] + adb), 80.f));
        bf16x8 hv = *(const bf16x8*)&h1[(size_t)s*256 + cl*8];
        z += w;
        acc8p(acc2, w, hv);
    }
    float acc[8];
    #pragma unroll
    for (int k = 0; k < 4; k++){ acc[2*k] = acc2[k][0]; acc[2*k+1] = acc2[k][1]; }
    #pragma unroll
    for (int j = 0; j < 8; j++) acc[j] += __shfl_xor(acc[j], 32);
    z += __shfl_xor(z, 32);
    float rz = 1.f / (z + 1e-16f);

    if (half == 0){
        int isb = *flag;
        bf16x8 bv = load8(b1, cl*8, isb);
        short ov[8];
        #pragma unroll
        for (int j = 0; j < 8; j++){
            float v = acc[j] * rz + bfbits(bv[j]);
            ov[j] = bf16s(v > 0.f ? v : expm1f(v));
        }
        *(bf16x8*)&x2[(size_t)n*256 + cl*8] = *(const bf16x8*)ov;
    }
}

// ---------------- GEMM2 (MFMA) + attention scalars layer 2 ----------------
__global__ __launch_bounds__(256) void k_gemm2(const bf16* __restrict__ x2,
        const bf16* __restrict__ Bp2, const void* __restrict__ attS,
        const void* __restrict__ attD, float* __restrict__ h2,
        float* __restrict__ a2s, float* __restrict__ a2d,
        const int* __restrict__ flag, int N){
    int t = threadIdx.x;
    int isb = *flag;
    int w = t >> 6, lane = t & 63;
    int m_lo = lane & 15, quad = lane >> 4;
    int m0 = blockIdx.x*64 + w*16;
    int mr = m0 + m_lo; if (mr >= N) mr = N-1;
    f32x4 acc = (f32x4){0.f,0.f,0.f,0.f};
    #pragma unroll
    for (int kt = 0; kt < 8; kt++){
        bf16x8 a = *(const bf16x8*)&x2[(size_t)mr*256 + kt*32 + quad*8];
        bf16x8 b = *(const bf16x8*)&Bp2[(size_t)(kt*64 + lane)*8];
        acc = __builtin_amdgcn_mfma_f32_16x16x32_bf16(a, b, acc, 0, 0, 0);
    }
    float s2 = (m_lo < 8) ? cvtf(attS, m_lo, isb) : 0.f;
    float d2 = (m_lo < 8) ? cvtf(attD, m_lo, isb) : 0.f;
    #pragma unroll
    for (int reg = 0; reg < 4; reg++){
        int m = m0 + quad*4 + reg;
        float val = acc[reg];
        float ps = val * s2, pd = val * d2;
        ps += __shfl_xor(ps, 1); ps += __shfl_xor(ps, 2);
        ps += __shfl_xor(ps, 4); ps += __shfl_xor(ps, 8);
        pd += __shfl_xor(pd, 1); pd += __shfl_xor(pd, 2);
        pd += __shfl_xor(pd, 4); pd += __shfl_xor(pd, 8);
        if (m < N){
            if (m_lo < 8) h2[(size_t)m*8 + m_lo] = val;
            if (m_lo == 0){ a2s[m] = ps; a2d[m] = pd; }
        }
    }
}

// ---------------- layer-2: single-sweep aggregate + bias + log_softmax (2-deep MLP) ----------------
__global__ __launch_bounds__(256) void k_edge2(const int* __restrict__ rowptr,
        const int* __restrict__ srcs, const float* __restrict__ a2s,
        const float* __restrict__ a2d, const float* __restrict__ h2,
        const void* __restrict__ b2, void* __restrict__ outv,
        const int* __restrict__ flag, int N){
    int t = threadIdx.x;
    int lane = t & 63, wv = t >> 6;
    int n = blockIdx.x*4 + wv;
    if (n >= N) return;
    int beg = rowptr[n];
    int deg = rowptr[n+1] - beg;
    float adh = a2d[n];
    int ep = lane >> 3, c = lane & 7;
    float acc = 0.f, z = 0.f;
    int e = ep;
    for (; e + 8 < deg; e += 16){
        int s0 = srcs[beg + e];
        int s1 = srcs[beg + e + 8];
        float w0 = __expf(fminf(lrelu(a2s[s0] + adh), 80.f));
        float w1 = __expf(fminf(lrelu(a2s[s1] + adh), 80.f));
        float g0 = h2[(size_t)s0*8 + c];
        float g1 = h2[(size_t)s1*8 + c];
        z += w0 + w1;
        acc += w0 * g0 + w1 * g1;
    }
    for (; e < deg; e += 8){
        int s = srcs[beg + e];
        float w = __expf(fminf(lrelu(a2s[s] + adh), 80.f));
        z += w;
        acc += w * h2[(size_t)s*8 + c];
    }
    acc += __shfl_xor(acc, 8);
    acc += __shfl_xor(acc, 16);
    acc += __shfl_xor(acc, 32);
    z += __shfl_xor(z, 8);
    z += __shfl_xor(z, 16);
    z += __shfl_xor(z, 32);
    int isb = *flag;
    float val = acc / (z + 1e-16f) + cvtf(b2, c, isb);
    float mx = val;
    mx = fmaxf(mx, __shfl_xor(mx, 1));
    mx = fmaxf(mx, __shfl_xor(mx, 2));
    mx = fmaxf(mx, __shfl_xor(mx, 4));
    float se = __expf(val - mx);
    se += __shfl_xor(se, 1); se += __shfl_xor(se, 2); se += __shfl_xor(se, 4);
    float r = val - mx - __logf(se);
    if (lane < 8){
        if (isb) ((bf16*)outv)[(size_t)n*8 + c] = f2bf(r);
        else     ((float*)outv)[(size_t)n*8 + c] = r;
    }
}

extern "C" void kernel_launch(void* const* d_in, const int* in_sizes, int n_in,
                              void* d_out, int out_size, void* d_ws, size_t ws_size,
                              hipStream_t stream) {
    const int* ei = (const int*)d_in[2];
    const int N = in_sizes[0] / 128;
    const int E = in_sizes[2] / 2;
    const int ET = E + N;
    const int NBUK = (N + 255) >> 8;

    char* p = (char*)d_ws;
    auto alloc = [&](size_t bytes) -> void* {
        char* r = p;
        p += (bytes + 255) & ~(size_t)255;
        return (void*)r;
    };
    int*   flag      = (int*)  alloc(256);
    int*   bucketCnt = (int*)  alloc((size_t)NBUK*4);
    int*   bucketPtr = (int*)  alloc((size_t)(NBUK+1)*4);
    int*   bucketCur = (int*)  alloc((size_t)NBUK*16*4);   // strided: 1 int per 64B
    int*   rowptr    = (int*)  alloc((size_t)(N+1)*4);
    int*   srcs      = (int*)  alloc((size_t)ET*4);
    int*   pk        = (int*)  alloc((size_t)E*4);
    bf16*  Bp        = (bf16*) alloc((size_t)192*256*2);
    bf16*  Bp2      = (bf16*) alloc((size_t)8*64*8*2);
    bf16*  emb       = (bf16*) alloc((size_t)N*64*2);
    bf16*  h1        = (bf16*) alloc((size_t)N*256*2);
    float* a_s       = (float*)alloc((size_t)N*8*4);
    float* a_d       = (float*)alloc((size_t)N*8*4);
    bf16*  x2        = (bf16*) alloc((size_t)N*256*2);
    float* h2        = (float*)alloc((size_t)N*8*4);
    float* a2s       = (float*)alloc((size_t)N*4);
    float* a2d       = (float*)alloc((size_t)N*4);

    hipMemsetAsync(bucketCnt, 0, (size_t)NBUK*4, stream);
    k_init<<<256, 256, 0, stream>>>((const unsigned short*)d_in[0], flag,
            ei + E, bucketCnt, E, NBUK, 256);
    {
        int nEmb  = (N + 127)/128;
        int nPack = (16*6*64*8 + 8*64*8 + 255)/256;
        k_prep<<<nEmb + nPack, 256, 0, stream>>>(d_in[1], d_in[3], d_in[4],
                d_in[5], d_in[9], emb, Bp, Bp2, flag, N, nEmb);
    }
    k_bscan<<<1, 256, 0, stream>>>(bucketCnt, bucketPtr, bucketCur, rowptr, N, E, NBUK);
    {
        int nG = (N + 63)/64;
        int nScat = (E + CHK - 1)/CHK;
        k_sg<<<nScat + nG, 256, 0, stream>>>(ei, bucketCur, pk,
                d_in[0], emb, Bp, d_in[6], d_in[7], h1, a_s, a_d, flag, N, E, nScat, NBUK);
    }
    k_fine<<<NBUK, 256, 0, stream>>>(bucketPtr, pk, rowptr, srcs, N);
    k_edge1<<<(N + 3)/4, 256, 0, stream>>>(rowptr, srcs, a_s, a_d, h1, d_in[8], x2, flag, N);
    k_gemm2<<<(N + 63)/64, 256, 0, stream>>>(x2, Bp2, d_in[10], d_in[11], h2, a2s, a2d, flag, N);
    k_edge2<<<(N + 3)/4, 256, 0, stream>>>(rowptr, srcs, a2s, a2d, h2, d_in[12], d_out, flag, N);
}

// Round 8
// 297.845 us; speedup vs baseline: 1.0617x; 1.0100x over previous
//
#include <hip/hip_runtime.h>
#include <hip/hip_bf16.h>

typedef __hip_bfloat16 bf16;
typedef short bf16x8 __attribute__((ext_vector_type(8)));
typedef float f32x4  __attribute__((ext_vector_type(4)));
typedef float f32x2  __attribute__((ext_vector_type(2)));
typedef int   i32x4  __attribute__((ext_vector_type(4)));

#define CHK 2048

__device__ __forceinline__ float bf2f(bf16 v){ return __bfloat162float(v); }
__device__ __forceinline__ bf16  f2bf(float f){ return __float2bfloat16(f); }
__device__ __forceinline__ float lrelu(float a){ return a > 0.f ? a : 0.2f*a; }
__device__ __forceinline__ float bfbits(short s){
    union{unsigned u; float f;} cv; cv.u = ((unsigned)(unsigned short)s) << 16; return cv.f;
}
__device__ __forceinline__ float fbits(int u){ union{int i; float f;} c; c.i = u; return c.f; }
__device__ __forceinline__ short bf16s(float f){ bf16 q = f2bf(f); return *(short*)&q; }
// polymorphic scalar reads (isb wave-uniform)
__device__ __forceinline__ float cvtf(const void* p, int i, int isb){
    return isb ? bf2f(((const bf16*)p)[i]) : ((const float*)p)[i];
}
__device__ __forceinline__ short cvts(const void* p, int i, int isb){
    return isb ? ((const short*)p)[i] : bf16s(((const float*)p)[i]);
}
// load 8 contiguous values as bf16x8 from either bf16 or f32 source
__device__ __forceinline__ bf16x8 load8(const void* base, size_t off, int isb){
    if (isb) return *(const bf16x8*)((const bf16*)base + off);
    const float* f = (const float*)base + off;
    f32x4 v0 = *(const f32x4*)f;
    f32x4 v1 = *(const f32x4*)(f + 4);
    short r[8];
    #pragma unroll
    for (int j = 0; j < 4; j++) r[j]   = bf16s(v0[j]);
    #pragma unroll
    for (int j = 0; j < 4; j++) r[4+j] = bf16s(v1[j]);
    return *(const bf16x8*)r;
}

// packed accumulate: acc2[k] holds channels {2k, 2k+1}; dword-wise bf16 unpack (1 op/ch)
__device__ __forceinline__ void acc8p(f32x2 acc2[4], float w, bf16x8 v){
    i32x4 iv = *(const i32x4*)&v;
    f32x2 w2 = {w, w};
    #pragma unroll
    for (int k = 0; k < 4; k++){
        int d = iv[k];
        f32x2 hv = {fbits(d << 16), fbits(d & 0xffff0000)};
        acc2[k] += w2 * hv;
    }
}

// ---------------- init: dtype detect (block 0) + coarse bucket histogram of dst ----------------
__global__ __launch_bounds__(256) void k_init(const unsigned short* __restrict__ raw,
        int* __restrict__ flag, const int* __restrict__ dst,
        int* __restrict__ bucketCnt, int E, int NBUK, int nBlk){
    __shared__ int h[256];
    int t = threadIdx.x;
    if (blockIdx.x == 0){
        unsigned short w = raw[2*t];
        int e = (w >> 7) & 0xFF;
        int ok = (e >= 90 && e <= 140) ? 1 : 0;
        __shared__ int cnt;
        if (t == 0) cnt = 0;
        __syncthreads();
        atomicAdd(&cnt, ok);
        __syncthreads();
        if (t == 0) *flag = (cnt >= 192) ? 1 : 0;  // 1 = bf16, 0 = f32
    }
    h[t] = 0;
    __syncthreads();
    for (int i = blockIdx.x*256 + t; i < E; i += nBlk*256)
        atomicAdd(&h[((unsigned)dst[i]) >> 8], 1);
    __syncthreads();
    if (t < NBUK && h[t]) atomicAdd(&bucketCnt[t], h[t]);
}

// ---------------- prep: emb (blocks<nEmb, 4 tiles each) | pack W1/W2 ----------------
__global__ __launch_bounds__(256) void k_prep(const void* __restrict__ low,
        const void* __restrict__ Wemb, const void* __restrict__ bemb,
        const void* __restrict__ W1, const void* __restrict__ W2,
        bf16* __restrict__ emb, bf16* __restrict__ Bp, bf16* __restrict__ Bp2,
        const int* __restrict__ flag, int N, int nEmb){
    __shared__ float wem[2048 + 64];
    __shared__ short lows[1024];
    int t = threadIdx.x;
    int b = blockIdx.x;
    int isb = *flag;
    if (b >= nEmb){
        // pack role
        int i = (b - nEmb)*256 + t;
        if (i < 16*6*64*8){
            int j = i & 7;
            int lane = (i >> 3) & 63;
            int r = i >> 9;
            int kt = r % 6, nt = r / 6;
            int k = kt*32 + (lane >> 4)*8 + j;
            int n = nt*16 + (lane & 15);
            *(short*)&Bp[i] = cvts(W1, k*256 + n, isb);
        } else {
            int i2 = i - 16*6*64*8;
            if (i2 >= 8*64*8) return;
            int j = i2 & 7;
            int lane = (i2 >> 3) & 63;
            int kt = i2 >> 9;
            int k = kt*32 + (lane >> 4)*8 + j;
            int n = lane & 15;
            *(short*)&Bp2[i2] = (n < 8) ? cvts(W2, k*8 + n, isb) : (short)0;
        }
        return;
    }
    // embedding role: four 32-node tiles sharing one W_emb load
    for (int i = t; i < 2048; i += 256) wem[i] = cvtf(Wemb, i, isb);
    if (t < 64) wem[2048 + t] = cvtf(bemb, t, isb);
    int nl = t >> 3, j8 = (t & 7) * 8;
    for (int tile = 0; tile < 4; tile++){
        int nb0 = b*128 + tile*32;
        __syncthreads();   // wem ready (tile 0) / previous tile compute done
        int lim = (N - nb0) * 32;
        if (lim > 1024) lim = 1024;
        if (lim < 0) lim = 0;
        for (int i = t; i < 1024; i += 256)
            lows[i] = (i < lim) ? cvts(low, nb0*32 + i, isb) : (short)0;
        __syncthreads();
        float acc[8];
        #pragma unroll
        for (int j = 0; j < 8; j++) acc[j] = wem[2048 + j8 + j];
        for (int k = 0; k < 32; k++){
            float lv = bfbits(lows[nl*32 + k]);
            f32x4 w0 = *(const f32x4*)&wem[k*64 + j8];
            f32x4 w1 = *(const f32x4*)&wem[k*64 + j8 + 4];
            #pragma unroll
            for (int j = 0; j < 4; j++) acc[j]   += lv * w0[j];
            #pragma unroll
            for (int j = 0; j < 4; j++) acc[4+j] += lv * w1[j];
        }
        int n = nb0 + nl;
        if (n < N){
            short ov[8];
            #pragma unroll
            for (int j = 0; j < 8; j++){
                float v = acc[j];
                ov[j] = bf16s(v > 0.f ? v : expm1f(v));
            }
            *(bf16x8*)&emb[(size_t)n*64 + j8] = *(const bf16x8*)ov;
        }
    }
}

// ---------------- single-block scan of coarse bucket counts ----------------
__global__ __launch_bounds__(256) void k_bscan(const int* __restrict__ bucketCnt,
        int* __restrict__ bucketPtr, int* __restrict__ bucketCur,
        int* __restrict__ rowptr, int N, int E, int NBUK){
    __shared__ int sd[256];
    int t = threadIdx.x;
    int v = (t < NBUK) ? bucketCnt[t] : 0;
    sd[t] = v;
    __syncthreads();
    #pragma unroll
    for (int off = 1; off < 256; off <<= 1){
        int a = (t >= off) ? sd[t - off] : 0;
        __syncthreads();
        sd[t] += a;
        __syncthreads();
    }
    int excl = sd[t] - v;
    if (t < NBUK){ bucketPtr[t] = excl; bucketCur[t*16] = excl; }  // cur strided: 1 int / 64B
    if (t == 0){ bucketPtr[NBUK] = sd[255]; rowptr[N] = E + N; }
}

// ---------------- merged: bucketed edge scatter (blocks < nScat) | GEMM1 (LDS-staged A) ----------------
__global__ __launch_bounds__(256) void k_sg(
        const int* __restrict__ ei, int* __restrict__ bucketCur, int* __restrict__ pk,
        const void* __restrict__ highv, const bf16* __restrict__ emb,
        const bf16* __restrict__ Bp, const void* __restrict__ attS,
        const void* __restrict__ attD, bf16* __restrict__ h1,
        float* __restrict__ a_s, float* __restrict__ a_d,
        const int* __restrict__ flag, int N, int E, int nScat, int NBUK){
    const int RS = 260;
    __shared__ union SM {
        struct { short Ah[64*128]; short Ae[64*64]; } a;                        // 24576B
        struct { float eb[16*260 + 16]; } g;                                     // 16704B (aliases Ah)
        struct { unsigned short dstS[CHK]; int hist[4][256]; int cur[4][256]; } s;// 12288B
    } sm;
    __shared__ float att[512];
    int t = threadIdx.x;
    if ((int)blockIdx.x < nScat){
        // ---- bucketed scatter role: pack (dstLow<<24 | src) grouped by dst>>8 ----
        int base = blockIdx.x * CHK;
        int cnt = E - base; if (cnt > CHK) cnt = CHK;
        int wv = t >> 6, lane = t & 63;
        #pragma unroll
        for (int w = 0; w < 4; w++) sm.s.hist[w][t] = 0;
        __syncthreads();
        const int* dstp = ei + E + base;
        const int* srcp = ei + base;
        int per = (cnt + 3) >> 2;
        int wb = wv*per, we = wb + per;
        if (we > cnt) we = cnt;
        if (wb > cnt) wb = cnt;
        for (int i = wb + lane; i < we; i += 64){
            int d = dstp[i];
            sm.s.dstS[i] = (unsigned short)d;
            atomicAdd(&sm.s.hist[wv][((unsigned)d) >> 8], 1);   // wave-private
        }
        __syncthreads();
        if (t < NBUK){
            int h0 = sm.s.hist[0][t], h1v = sm.s.hist[1][t];
            int h2 = sm.s.hist[2][t], h3 = sm.s.hist[3][t];
            int c = h0 + h1v + h2 + h3;
            int bs = c ? atomicAdd(&bucketCur[t*16], c) : 0;
            sm.s.cur[0][t] = bs;
            sm.s.cur[1][t] = bs + h0;
            sm.s.cur[2][t] = bs + h0 + h1v;
            sm.s.cur[3][t] = bs + h0 + h1v + h2;
        }
        __syncthreads();
        for (int i = wb + lane; i < we; i += 64){
            int d = sm.s.dstS[i];
            int pos = atomicAdd(&sm.s.cur[wv][d >> 8], 1);      // wave-private
            pk[pos] = ((d & 255) << 24) | srcp[i];
        }
        return;
    }
    // ---- GEMM1 role ----
    int isb = *flag;
    att[t] = cvtf(attS, t, isb);
    att[256 + t] = cvtf(attD, t, isb);
    int w = t >> 6, lane = t & 63;
    int m_lo = lane & 15, quad = lane >> 4;
    int m0 = (blockIdx.x - nScat) * 64;

    // ---- stage A (high 64x128 + emb 64x64) into XOR-swizzled LDS, coalesced ----
    #pragma unroll
    for (int ii = 0; ii < 4; ii++){
        int id = t + ii*256;            // 0..1023
        int r = id >> 4, c = id & 15;
        int gr = m0 + r; if (gr >= N) gr = N-1;
        bf16x8 v = load8(highv, (size_t)gr*128 + c*8, isb);
        *(bf16x8*)&sm.a.Ah[r*128 + ((c ^ (r & 7)) << 3)] = v;
    }
    #pragma unroll
    for (int ii = 0; ii < 2; ii++){
        int id = t + ii*256;            // 0..511
        int r = id >> 3, c = id & 7;
        int gr = m0 + r; if (gr >= N) gr = N-1;
        bf16x8 v = *(const bf16x8*)&emb[(size_t)gr*64 + c*8];
        *(bf16x8*)&sm.a.Ae[r*64 + ((c ^ (r & 7)) << 3)] = v;
    }
    __syncthreads();

    f32x4 acc[4][4];
    #pragma unroll
    for (int rt = 0; rt < 4; rt++)
        #pragma unroll
        for (int ct = 0; ct < 4; ct++) acc[rt][ct] = (f32x4){0.f,0.f,0.f,0.f};

    int sw = m_lo & 7;   // row-XOR for fragment reads
    #pragma unroll 2
    for (int kt = 0; kt < 6; kt++){
        bf16x8 a[4], b[4];
        if (kt < 4){
            int ch = (kt*4 + quad) ^ sw;
            #pragma unroll
            for (int rt = 0; rt < 4; rt++)
                a[rt] = *(const bf16x8*)&sm.a.Ah[(rt*16 + m_lo)*128 + (ch << 3)];
        } else {
            int ch = ((kt-4)*4 + quad) ^ sw;
            #pragma unroll
            for (int rt = 0; rt < 4; rt++)
                a[rt] = *(const bf16x8*)&sm.a.Ae[(rt*16 + m_lo)*64 + (ch << 3)];
        }
        #pragma unroll
        for (int ct = 0; ct < 4; ct++)
            b[ct] = *(const bf16x8*)&Bp[(size_t)(((w*4 + ct)*6 + kt)*64 + lane)*8];
        #pragma unroll
        for (int rt = 0; rt < 4; rt++)
            #pragma unroll
            for (int ct = 0; ct < 4; ct++)
                acc[rt][ct] = __builtin_amdgcn_mfma_f32_16x16x32_bf16(a[rt], b[ct], acc[rt][ct], 0, 0, 0);
    }

    float* eb = sm.g.eb;   // aliases Ah — safe: barriers below separate all uses
    #pragma unroll 1
    for (int rt = 0; rt < 4; rt++){
        __syncthreads();
        #pragma unroll
        for (int ct = 0; ct < 4; ct++)
            #pragma unroll
            for (int reg = 0; reg < 4; reg++)
                eb[(quad*4 + reg)*RS + w*64 + ct*16 + m_lo] = acc[rt][ct][reg];
        __syncthreads();
        int r = t >> 4, cb = t & 15;
        int c0 = cb * 16;
        int m = m0 + rt*16 + r;
        f32x4 v[4];
        #pragma unroll
        for (int p = 0; p < 4; p++) v[p] = *(const f32x4*)&eb[r*RS + c0 + p*4];
        float ps = 0.f, pd = 0.f;
        #pragma unroll
        for (int p = 0; p < 4; p++)
            #pragma unroll
            for (int j = 0; j < 4; j++){
                ps += v[p][j] * att[c0 + p*4 + j];
                pd += v[p][j] * att[256 + c0 + p*4 + j];
            }
        if (m < N){
            short ov[16];
            #pragma unroll
            for (int p = 0; p < 4; p++)
                #pragma unroll
                for (int j = 0; j < 4; j++) ov[p*4+j] = bf16s(v[p][j]);
            *(bf16x8*)&h1[(size_t)m*256 + c0]     = *(const bf16x8*)&ov[0];
            *(bf16x8*)&h1[(size_t)m*256 + c0 + 8] = *(const bf16x8*)&ov[8];
        }
        ps += __shfl_xor(ps, 1);
        pd += __shfl_xor(pd, 1);
        if (((t & 1) == 0) && m < N){
            int hd = cb >> 1;
            a_s[m*8 + hd] = ps;
            a_d[m*8 + hd] = pd;
        }
    }
}

// ---------------- fine pass: per-bucket dst counts (wave-private), scan, self-loops, final scatter ----------------
__global__ __launch_bounds__(256) void k_fine(const int* __restrict__ bucketPtr,
        const int* __restrict__ pk, int* __restrict__ rowptr, int* __restrict__ srcs,
        int N){
    __shared__ int hist[4][256];
    __shared__ int cur[4][256];
    __shared__ int sd[256];
    int t = threadIdx.x;
    int wv = t >> 6, lane = t & 63;
    int b = blockIdx.x;
    int d0 = b << 8;
    int nd = N - d0; if (nd > 256) nd = 256; if (nd < 0) nd = 0;
    int ebeg = bucketPtr[b], eend = bucketPtr[b+1];
    int tot = eend - ebeg;
    int per = (tot + 3) >> 2;
    int wb = wv*per, we = wb + per;
    if (we > tot) we = tot;
    if (wb > tot) wb = tot;
    #pragma unroll
    for (int w = 0; w < 4; w++) hist[w][t] = 0;
    __syncthreads();
    for (int i = wb + lane; i < we; i += 64)
        atomicAdd(&hist[wv][((unsigned)pk[ebeg + i]) >> 24], 1);   // wave-private
    __syncthreads();
    int h0 = hist[0][t], h1 = hist[1][t], h2 = hist[2][t], h3 = hist[3][t];
    int selfc = (t < nd) ? 1 : 0;
    int v = selfc + h0 + h1 + h2 + h3;
    sd[t] = v;
    __syncthreads();
    #pragma unroll
    for (int off = 1; off < 256; off <<= 1){
        int a = (t >= off) ? sd[t - off] : 0;
        __syncthreads();
        sd[t] += a;
        __syncthreads();
    }
    int r = ebeg + d0 + sd[t] - v;   // prior self-loops = d0 (all earlier buckets full)
    if (t < nd){
        rowptr[d0 + t] = r;
        srcs[r] = d0 + t;            // self-loop at segment head
    }
    int c0 = r + selfc;
    cur[0][t] = c0;
    cur[1][t] = c0 + h0;
    cur[2][t] = c0 + h0 + h1;
    cur[3][t] = c0 + h0 + h1 + h2;
    __syncthreads();
    for (int i = wb + lane; i < we; i += 64){
        int p = pk[ebeg + i];
        int pos = atomicAdd(&cur[wv][((unsigned)p) >> 24], 1);     // wave-private
        srcs[pos] = p & 0xFFFFFF;
    }
}

// ---------------- layer-1: software-pipelined aggregate (srcs/a_s lookahead) + elu + bias ----------------
__global__ __launch_bounds__(256) void k_edge1(const int* __restrict__ rowptr,
        const int* __restrict__ srcs, const float* __restrict__ a_s,
        const float* __restrict__ a_d, const bf16* __restrict__ h1,
        const void* __restrict__ b1, bf16* __restrict__ x2,
        const int* __restrict__ flag, int N){
    int t = threadIdx.x;
    int lane = t & 63, wv = t >> 6;
    int n = blockIdx.x*4 + wv;
    if (n >= N) return;
    int beg = rowptr[n];
    int deg = rowptr[n+1] - beg;

    int cl = lane & 31;          // channel group: channels cl*8..cl*8+7
    int hb = cl >> 2;            // head of this group
    int half = lane >> 5;        // edge parity
    float adb = a_d[n*8 + hb];

    f32x2 acc2[4];
    #pragma unroll
    for (int k = 0; k < 4; k++) acc2[k] = (f32x2){0.f, 0.f};
    float z = 0.f;

    int e = half;
    if (e + 6 < deg){
        // prologue: indices + att values for chunk 0
        int s0 = srcs[beg + e];
        int s1 = srcs[beg + e + 2];
        int s2 = srcs[beg + e + 4];
        int s3 = srcs[beg + e + 6];
        float a0 = a_s[s0*8 + hb];
        float a1 = a_s[s1*8 + hb];
        float a2 = a_s[s2*8 + hb];
        float a3 = a_s[s3*8 + hb];
        while (true){
            // issue current h1 gathers (indices already resident)
            bf16x8 v0 = *(const bf16x8*)&h1[(size_t)s0*256 + cl*8];
            bf16x8 v1 = *(const bf16x8*)&h1[(size_t)s1*256 + cl*8];
            bf16x8 v2 = *(const bf16x8*)&h1[(size_t)s2*256 + cl*8];
            bf16x8 v3 = *(const bf16x8*)&h1[(size_t)s3*256 + cl*8];
            int en = e + 8;
            bool more = (en + 6 < deg);    // wave-uniform
            int n0, n1, n2, n3;
            float b0, b1, b2, b3;
            if (more){
                // lookahead: next chunk indices + att values fly under current compute
                n0 = srcs[beg + en];
                n1 = srcs[beg + en + 2];
                n2 = srcs[beg + en + 4];
                n3 = srcs[beg + en + 6];
                b0 = a_s[n0*8 + hb];
                b1 = a_s[n1*8 + hb];
                b2 = a_s[n2*8 + hb];
                b3 = a_s[n3*8 + hb];
            }
            // weights from resident att values (VALU overlaps gather latency)
            float w0 = __expf(fminf(lrelu(a0 + adb), 80.f));
            float w1 = __expf(fminf(lrelu(a1 + adb), 80.f));
            float w2 = __expf(fminf(lrelu(a2 + adb), 80.f));
            float w3 = __expf(fminf(lrelu(a3 + adb), 80.f));
            z += (w0 + w1) + (w2 + w3);
            acc8p(acc2, w0, v0);
            acc8p(acc2, w1, v1);
            acc8p(acc2, w2, v2);
            acc8p(acc2, w3, v3);
            e = en;
            if (!more) break;
            s0 = n0; s1 = n1; s2 = n2; s3 = n3;
            a0 = b0; a1 = b1; a2 = b2; a3 = b3;
        }
    }
    for (; e < deg; e += 2){
        int s = srcs[beg + e];
        float w = __expf(fminf(lrelu(a_s[s*8 + hb] + adb), 80.f));
        bf16x8 hv = *(const bf16x8*)&h1[(size_t)s*256 + cl*8];
        z += w;
        acc8p(acc2, w, hv);
    }
    float acc[8];
    #pragma unroll
    for (int k = 0; k < 4; k++){ acc[2*k] = acc2[k][0]; acc[2*k+1] = acc2[k][1]; }
    #pragma unroll
    for (int j = 0; j < 8; j++) acc[j] += __shfl_xor(acc[j], 32);
    z += __shfl_xor(z, 32);
    float rz = 1.f / (z + 1e-16f);

    if (half == 0){
        int isb = *flag;
        bf16x8 bv = load8(b1, cl*8, isb);
        short ov[8];
        #pragma unroll
        for (int j = 0; j < 8; j++){
            float v = acc[j] * rz + bfbits(bv[j]);
            ov[j] = bf16s(v > 0.f ? v : expm1f(v));
        }
        *(bf16x8*)&x2[(size_t)n*256 + cl*8] = *(const bf16x8*)ov;
    }
}

// ---------------- GEMM2 (MFMA) + attention scalars layer 2 ----------------
__global__ __launch_bounds__(256) void k_gemm2(const bf16* __restrict__ x2,
        const bf16* __restrict__ Bp2, const void* __restrict__ attS,
        const void* __restrict__ attD, float* __restrict__ h2,
        float* __restrict__ a2s, float* __restrict__ a2d,
        const int* __restrict__ flag, int N){
    int t = threadIdx.x;
    int isb = *flag;
    int w = t >> 6, lane = t & 63;
    int m_lo = lane & 15, quad = lane >> 4;
    int m0 = blockIdx.x*64 + w*16;
    int mr = m0 + m_lo; if (mr >= N) mr = N-1;
    f32x4 acc = (f32x4){0.f,0.f,0.f,0.f};
    #pragma unroll
    for (int kt = 0; kt < 8; kt++){
        bf16x8 a = *(const bf16x8*)&x2[(size_t)mr*256 + kt*32 + quad*8];
        bf16x8 b = *(const bf16x8*)&Bp2[(size_t)(kt*64 + lane)*8];
        acc = __builtin_amdgcn_mfma_f32_16x16x32_bf16(a, b, acc, 0, 0, 0);
    }
    float s2 = (m_lo < 8) ? cvtf(attS, m_lo, isb) : 0.f;
    float d2 = (m_lo < 8) ? cvtf(attD, m_lo, isb) : 0.f;
    #pragma unroll
    for (int reg = 0; reg < 4; reg++){
        int m = m0 + quad*4 + reg;
        float val = acc[reg];
        float ps = val * s2, pd = val * d2;
        ps += __shfl_xor(ps, 1); ps += __shfl_xor(ps, 2);
        ps += __shfl_xor(ps, 4); ps += __shfl_xor(ps, 8);
        pd += __shfl_xor(pd, 1); pd += __shfl_xor(pd, 2);
        pd += __shfl_xor(pd, 4); pd += __shfl_xor(pd, 8);
        if (m < N){
            if (m_lo < 8) h2[(size_t)m*8 + m_lo] = val;
            if (m_lo == 0){ a2s[m] = ps; a2d[m] = pd; }
        }
    }
}

// ---------------- layer-2: software-pipelined aggregate + bias + log_softmax ----------------
__global__ __launch_bounds__(256) void k_edge2(const int* __restrict__ rowptr,
        const int* __restrict__ srcs, const float* __restrict__ a2s,
        const float* __restrict__ a2d, const float* __restrict__ h2,
        const void* __restrict__ b2, void* __restrict__ outv,
        const int* __restrict__ flag, int N){
    int t = threadIdx.x;
    int lane = t & 63, wv = t >> 6;
    int n = blockIdx.x*4 + wv;
    if (n >= N) return;
    int beg = rowptr[n];
    int deg = rowptr[n+1] - beg;
    float adh = a2d[n];
    int ep = lane >> 3, c = lane & 7;
    float acc = 0.f, z = 0.f;
    int e = ep;
    if (e + 8 < deg){
        int s0 = srcs[beg + e];
        int s1 = srcs[beg + e + 8];
        float a0 = a2s[s0], a1 = a2s[s1];
        float g0 = h2[(size_t)s0*8 + c], g1 = h2[(size_t)s1*8 + c];
        while (true){
            int en = e + 16;
            bool more = (en + 8 < deg);    // wave-uniform
            int n0, n1; float b0, b1, f0, f1;
            if (more){
                n0 = srcs[beg + en];
                n1 = srcs[beg + en + 8];
                b0 = a2s[n0]; b1 = a2s[n1];
                f0 = h2[(size_t)n0*8 + c]; f1 = h2[(size_t)n1*8 + c];
            }
            float w0 = __expf(fminf(lrelu(a0 + adh), 80.f));
            float w1 = __expf(fminf(lrelu(a1 + adh), 80.f));
            z += w0 + w1;
            acc += w0 * g0 + w1 * g1;
            e = en;
            if (!more) break;
            s0 = n0; s1 = n1; a0 = b0; a1 = b1; g0 = f0; g1 = f1;
        }
    }
    for (; e < deg; e += 8){
        int s = srcs[beg + e];
        float w = __expf(fminf(lrelu(a2s[s] + adh), 80.f));
        z += w;
        acc += w * h2[(size_t)s*8 + c];
    }
    acc += __shfl_xor(acc, 8);
    acc += __shfl_xor(acc, 16);
    acc += __shfl_xor(acc, 32);
    z += __shfl_xor(z, 8);
    z += __shfl_xor(z, 16);
    z += __shfl_xor(z, 32);
    int isb = *flag;
    float val = acc / (z + 1e-16f) + cvtf(b2, c, isb);
    float mx = val;
    mx = fmaxf(mx, __shfl_xor(mx, 1));
    mx = fmaxf(mx, __shfl_xor(mx, 2));
    mx = fmaxf(mx, __shfl_xor(mx, 4));
    float se = __expf(val - mx);
    se += __shfl_xor(se, 1); se += __shfl_xor(se, 2); se += __shfl_xor(se, 4);
    float r = val - mx - __logf(se);
    if (lane < 8){
        if (isb) ((bf16*)outv)[(size_t)n*8 + c] = f2bf(r);
        else     ((float*)outv)[(size_t)n*8 + c] = r;
    }
}

extern "C" void kernel_launch(void* const* d_in, const int* in_sizes, int n_in,
                              void* d_out, int out_size, void* d_ws, size_t ws_size,
                              hipStream_t stream) {
    const int* ei = (const int*)d_in[2];
    const int N = in_sizes[0] / 128;
    const int E = in_sizes[2] / 2;
    const int ET = E + N;
    const int NBUK = (N + 255) >> 8;

    char* p = (char*)d_ws;
    auto alloc = [&](size_t bytes) -> void* {
        char* r = p;
        p += (bytes + 255) & ~(size_t)255;
        return (void*)r;
    };
    int*   flag      = (int*)  alloc(256);
    int*   bucketCnt = (int*)  alloc((size_t)NBUK*4);
    int*   bucketPtr = (int*)  alloc((size_t)(NBUK+1)*4);
    int*   bucketCur = (int*)  alloc((size_t)NBUK*16*4);   // strided: 1 int per 64B
    int*   rowptr    = (int*)  alloc((size_t)(N+1)*4);
    int*   srcs      = (int*)  alloc((size_t)ET*4);
    int*   pk        = (int*)  alloc((size_t)E*4);
    bf16*  Bp        = (bf16*) alloc((size_t)192*256*2);
    bf16*  Bp2      = (bf16*) alloc((size_t)8*64*8*2);
    bf16*  emb       = (bf16*) alloc((size_t)N*64*2);
    bf16*  h1        = (bf16*) alloc((size_t)N*256*2);
    float* a_s       = (float*)alloc((size_t)N*8*4);
    float* a_d       = (float*)alloc((size_t)N*8*4);
    bf16*  x2        = (bf16*) alloc((size_t)N*256*2);
    float* h2        = (float*)alloc((size_t)N*8*4);
    float* a2s       = (float*)alloc((size_t)N*4);
    float* a2d       = (float*)alloc((size_t)N*4);

    hipMemsetAsync(bucketCnt, 0, (size_t)NBUK*4, stream);
    k_init<<<256, 256, 0, stream>>>((const unsigned short*)d_in[0], flag,
            ei + E, bucketCnt, E, NBUK, 256);
    {
        int nEmb  = (N + 127)/128;
        int nPack = (16*6*64*8 + 8*64*8 + 255)/256;
        k_prep<<<nEmb + nPack, 256, 0, stream>>>(d_in[1], d_in[3], d_in[4],
                d_in[5], d_in[9], emb, Bp, Bp2, flag, N, nEmb);
    }
    k_bscan<<<1, 256, 0, stream>>>(bucketCnt, bucketPtr, bucketCur, rowptr, N, E, NBUK);
    {
        int nG = (N + 63)/64;
        int nScat = (E + CHK - 1)/CHK;
        k_sg<<<nScat + nG, 256, 0, stream>>>(ei, bucketCur, pk,
                d_in[0], emb, Bp, d_in[6], d_in[7], h1, a_s, a_d, flag, N, E, nScat, NBUK);
    }
    k_fine<<<NBUK, 256, 0, stream>>>(bucketPtr, pk, rowptr, srcs, N);
    k_edge1<<<(N + 3)/4, 256, 0, stream>>>(rowptr, srcs, a_s, a_d, h1, d_in[8], x2, flag, N);
    k_gemm2<<<(N + 63)/64, 256, 0, stream>>>(x2, Bp2, d_in[10], d_in[11], h2, a2s, a2d, flag, N);
    k_edge2<<<(N + 3)/4, 256, 0, stream>>>(rowptr, srcs, a2s, a2d, h2, d_in[12], d_out, flag, N);
}

// Round 9
// 297.499 us; speedup vs baseline: 1.0630x; 1.0012x over previous
//
#include <hip/hip_runtime.h>
#include <hip/hip_bf16.h>

typedef __hip_bfloat16 bf16;
typedef short bf16x8 __attribute__((ext_vector_type(8)));
typedef float f32x4  __attribute__((ext_vector_type(4)));
typedef float f32x2  __attribute__((ext_vector_type(2)));
typedef int   i32x4  __attribute__((ext_vector_type(4)));

#define CHK 2048

__device__ __forceinline__ float bf2f(bf16 v){ return __bfloat162float(v); }
__device__ __forceinline__ bf16  f2bf(float f){ return __float2bfloat16(f); }
__device__ __forceinline__ float lrelu(float a){ return a > 0.f ? a : 0.2f*a; }
__device__ __forceinline__ float bfbits(short s){
    union{unsigned u; float f;} cv; cv.u = ((unsigned)(unsigned short)s) << 16; return cv.f;
}
__device__ __forceinline__ float fbits(int u){ union{int i; float f;} c; c.i = u; return c.f; }
__device__ __forceinline__ short bf16s(float f){ bf16 q = f2bf(f); return *(short*)&q; }
// polymorphic scalar reads (isb wave-uniform)
__device__ __forceinline__ float cvtf(const void* p, int i, int isb){
    return isb ? bf2f(((const bf16*)p)[i]) : ((const float*)p)[i];
}
__device__ __forceinline__ short cvts(const void* p, int i, int isb){
    return isb ? ((const short*)p)[i] : bf16s(((const float*)p)[i]);
}
// load 8 contiguous values as bf16x8 from either bf16 or f32 source
__device__ __forceinline__ bf16x8 load8(const void* base, size_t off, int isb){
    if (isb) return *(const bf16x8*)((const bf16*)base + off);
    const float* f = (const float*)base + off;
    f32x4 v0 = *(const f32x4*)f;
    f32x4 v1 = *(const f32x4*)(f + 4);
    short r[8];
    #pragma unroll
    for (int j = 0; j < 4; j++) r[j]   = bf16s(v0[j]);
    #pragma unroll
    for (int j = 0; j < 4; j++) r[4+j] = bf16s(v1[j]);
    return *(const bf16x8*)r;
}

// packed accumulate: acc2[k] holds channels {2k, 2k+1}; dword-wise bf16 unpack (1 op/ch)
__device__ __forceinline__ void acc8p(f32x2 acc2[4], float w, bf16x8 v){
    i32x4 iv = *(const i32x4*)&v;
    f32x2 w2 = {w, w};
    #pragma unroll
    for (int k = 0; k < 4; k++){
        int d = iv[k];
        f32x2 hv = {fbits(d << 16), fbits(d & 0xffff0000)};
        acc2[k] += w2 * hv;
    }
}

// ---------------- merged prep: emb (4 tiles/blk) | pack W1/W2 | dst histogram; per-block dtype detect ----------------
__global__ __launch_bounds__(256) void k_prep(const unsigned short* __restrict__ raw,
        const void* __restrict__ low,
        const void* __restrict__ Wemb, const void* __restrict__ bemb,
        const void* __restrict__ W1, const void* __restrict__ W2,
        bf16* __restrict__ emb, bf16* __restrict__ Bp, bf16* __restrict__ Bp2,
        const int* __restrict__ dst, int* __restrict__ bucketCnt,
        int* __restrict__ flag, int N, int E, int nEmb, int nPack, int nCnt, int NBUK){
    __shared__ float wem[2048 + 64];
    __shared__ short lows[1024];
    __shared__ int hh[256];
    __shared__ int cnt;
    int t = threadIdx.x;
    int b = blockIdx.x;
    if (b >= nEmb + nPack){
        // histogram role (no dtype needed)
        int cb = b - nEmb - nPack;
        hh[t] = 0;
        __syncthreads();
        for (int i = cb*256 + t; i < E; i += nCnt*256)
            atomicAdd(&hh[((unsigned)dst[i]) >> 8], 1);
        __syncthreads();
        if (t < NBUK && hh[t]) atomicAdd(&bucketCnt[t], hh[t]);
        return;
    }
    // per-block dtype detect (raw = high-feature words; bf16 exponents cluster in [90,140])
    {
        unsigned short wd = raw[2*t];
        int ex = (wd >> 7) & 0xFF;
        int ok = (ex >= 90 && ex <= 140) ? 1 : 0;
        if (t == 0) cnt = 0;
        __syncthreads();
        atomicAdd(&cnt, ok);
        __syncthreads();
    }
    int isb = (cnt >= 192) ? 1 : 0;
    if (b == 0 && t == 0) *flag = isb;   // publish for downstream kernels
    if (b >= nEmb){
        // pack role
        int i = (b - nEmb)*256 + t;
        if (i < 16*6*64*8){
            int j = i & 7;
            int lane = (i >> 3) & 63;
            int r = i >> 9;
            int kt = r % 6, nt = r / 6;
            int k = kt*32 + (lane >> 4)*8 + j;
            int n = nt*16 + (lane & 15);
            *(short*)&Bp[i] = cvts(W1, k*256 + n, isb);
        } else {
            int i2 = i - 16*6*64*8;
            if (i2 >= 8*64*8) return;
            int j = i2 & 7;
            int lane = (i2 >> 3) & 63;
            int kt = i2 >> 9;
            int k = kt*32 + (lane >> 4)*8 + j;
            int n = lane & 15;
            *(short*)&Bp2[i2] = (n < 8) ? cvts(W2, k*8 + n, isb) : (short)0;
        }
        return;
    }
    // embedding role: four 32-node tiles sharing one W_emb load
    for (int i = t; i < 2048; i += 256) wem[i] = cvtf(Wemb, i, isb);
    if (t < 64) wem[2048 + t] = cvtf(bemb, t, isb);
    int nl = t >> 3, j8 = (t & 7) * 8;
    for (int tile = 0; tile < 4; tile++){
        int nb0 = b*128 + tile*32;
        __syncthreads();   // wem ready (tile 0) / previous tile compute done
        int lim = (N - nb0) * 32;
        if (lim > 1024) lim = 1024;
        if (lim < 0) lim = 0;
        for (int i = t; i < 1024; i += 256)
            lows[i] = (i < lim) ? cvts(low, nb0*32 + i, isb) : (short)0;
        __syncthreads();
        float acc[8];
        #pragma unroll
        for (int j = 0; j < 8; j++) acc[j] = wem[2048 + j8 + j];
        for (int k = 0; k < 32; k++){
            float lv = bfbits(lows[nl*32 + k]);
            f32x4 w0 = *(const f32x4*)&wem[k*64 + j8];
            f32x4 w1 = *(const f32x4*)&wem[k*64 + j8 + 4];
            #pragma unroll
            for (int j = 0; j < 4; j++) acc[j]   += lv * w0[j];
            #pragma unroll
            for (int j = 0; j < 4; j++) acc[4+j] += lv * w1[j];
        }
        int n = nb0 + nl;
        if (n < N){
            short ov[8];
            #pragma unroll
            for (int j = 0; j < 8; j++){
                float v = acc[j];
                ov[j] = bf16s(v > 0.f ? v : expm1f(v));
            }
            *(bf16x8*)&emb[(size_t)n*64 + j8] = *(const bf16x8*)ov;
        }
    }
}

// ---------------- single-block scan of coarse bucket counts ----------------
__global__ __launch_bounds__(256) void k_bscan(const int* __restrict__ bucketCnt,
        int* __restrict__ bucketPtr, int* __restrict__ bucketCur,
        int* __restrict__ rowptr, int N, int E, int NBUK){
    __shared__ int sd[256];
    int t = threadIdx.x;
    int v = (t < NBUK) ? bucketCnt[t] : 0;
    sd[t] = v;
    __syncthreads();
    #pragma unroll
    for (int off = 1; off < 256; off <<= 1){
        int a = (t >= off) ? sd[t - off] : 0;
        __syncthreads();
        sd[t] += a;
        __syncthreads();
    }
    int excl = sd[t] - v;
    if (t < NBUK){ bucketPtr[t] = excl; bucketCur[t*16] = excl; }  // cur strided: 1 int / 64B
    if (t == 0){ bucketPtr[NBUK] = sd[255]; rowptr[N] = E + N; }
}

// ---------------- merged: bucketed edge scatter (blocks < nScat) | GEMM1 (LDS-staged A) ----------------
__global__ __launch_bounds__(256) void k_sg(
        const int* __restrict__ ei, int* __restrict__ bucketCur, int* __restrict__ pk,
        const void* __restrict__ highv, const bf16* __restrict__ emb,
        const bf16* __restrict__ Bp, const void* __restrict__ attS,
        const void* __restrict__ attD, bf16* __restrict__ h1,
        float* __restrict__ a_s, float* __restrict__ a_d,
        const int* __restrict__ flag, int N, int E, int nScat, int NBUK){
    const int CS  = 17;            // padded chunk stride (floats): 16 data + 1 pad
    const int RSS = 16*CS + 4;     // 276 floats per epilogue row
    __shared__ union SM {
        struct { short Ah[64*128]; short Ae[64*64]; } a;                        // 24576B
        struct { float eb[16*276 + 16]; } g;                                     // 17728B (aliases Ah)
        struct { unsigned short dstS[CHK]; int hist[4][256]; int cur[4][256]; } s;// 12288B
    } sm;
    __shared__ float att[512];
    int t = threadIdx.x;
    if ((int)blockIdx.x < nScat){
        // ---- bucketed scatter role: pack (dstLow<<24 | src) grouped by dst>>8 ----
        int base = blockIdx.x * CHK;
        int cnt = E - base; if (cnt > CHK) cnt = CHK;
        int wv = t >> 6, lane = t & 63;
        #pragma unroll
        for (int w = 0; w < 4; w++) sm.s.hist[w][t] = 0;
        __syncthreads();
        const int* dstp = ei + E + base;
        const int* srcp = ei + base;
        int per = (cnt + 3) >> 2;
        int wb = wv*per, we = wb + per;
        if (we > cnt) we = cnt;
        if (wb > cnt) wb = cnt;
        for (int i = wb + lane; i < we; i += 64){
            int d = dstp[i];
            sm.s.dstS[i] = (unsigned short)d;
            atomicAdd(&sm.s.hist[wv][((unsigned)d) >> 8], 1);   // wave-private
        }
        __syncthreads();
        if (t < NBUK){
            int h0 = sm.s.hist[0][t], h1v = sm.s.hist[1][t];
            int h2 = sm.s.hist[2][t], h3 = sm.s.hist[3][t];
            int c = h0 + h1v + h2 + h3;
            int bs = c ? atomicAdd(&bucketCur[t*16], c) : 0;
            sm.s.cur[0][t] = bs;
            sm.s.cur[1][t] = bs + h0;
            sm.s.cur[2][t] = bs + h0 + h1v;
            sm.s.cur[3][t] = bs + h0 + h1v + h2;
        }
        __syncthreads();
        for (int i = wb + lane; i < we; i += 64){
            int d = sm.s.dstS[i];
            int pos = atomicAdd(&sm.s.cur[wv][d >> 8], 1);      // wave-private
            pk[pos] = ((d & 255) << 24) | srcp[i];
        }
        return;
    }
    // ---- GEMM1 role ----
    int isb = *flag;
    att[t] = cvtf(attS, t, isb);
    att[256 + t] = cvtf(attD, t, isb);
    int w = t >> 6, lane = t & 63;
    int m_lo = lane & 15, quad = lane >> 4;
    int m0 = (blockIdx.x - nScat) * 64;

    // ---- stage A (high 64x128 + emb 64x64) into XOR-swizzled LDS, coalesced ----
    #pragma unroll
    for (int ii = 0; ii < 4; ii++){
        int id = t + ii*256;            // 0..1023
        int r = id >> 4, c = id & 15;
        int gr = m0 + r; if (gr >= N) gr = N-1;
        bf16x8 v = load8(highv, (size_t)gr*128 + c*8, isb);
        *(bf16x8*)&sm.a.Ah[r*128 + ((c ^ (r & 7)) << 3)] = v;
    }
    #pragma unroll
    for (int ii = 0; ii < 2; ii++){
        int id = t + ii*256;            // 0..511
        int r = id >> 3, c = id & 7;
        int gr = m0 + r; if (gr >= N) gr = N-1;
        bf16x8 v = *(const bf16x8*)&emb[(size_t)gr*64 + c*8];
        *(bf16x8*)&sm.a.Ae[r*64 + ((c ^ (r & 7)) << 3)] = v;
    }
    __syncthreads();

    f32x4 acc[4][4];
    #pragma unroll
    for (int rt = 0; rt < 4; rt++)
        #pragma unroll
        for (int ct = 0; ct < 4; ct++) acc[rt][ct] = (f32x4){0.f,0.f,0.f,0.f};

    int sw = m_lo & 7;   // row-XOR for fragment reads
    #pragma unroll 2
    for (int kt = 0; kt < 6; kt++){
        bf16x8 a[4], b[4];
        if (kt < 4){
            int ch = (kt*4 + quad) ^ sw;
            #pragma unroll
            for (int rt = 0; rt < 4; rt++)
                a[rt] = *(const bf16x8*)&sm.a.Ah[(rt*16 + m_lo)*128 + (ch << 3)];
        } else {
            int ch = ((kt-4)*4 + quad) ^ sw;
            #pragma unroll
            for (int rt = 0; rt < 4; rt++)
                a[rt] = *(const bf16x8*)&sm.a.Ae[(rt*16 + m_lo)*64 + (ch << 3)];
        }
        #pragma unroll
        for (int ct = 0; ct < 4; ct++)
            b[ct] = *(const bf16x8*)&Bp[(size_t)(((w*4 + ct)*6 + kt)*64 + lane)*8];
        #pragma unroll
        for (int rt = 0; rt < 4; rt++)
            #pragma unroll
            for (int ct = 0; ct < 4; ct++)
                acc[rt][ct] = __builtin_amdgcn_mfma_f32_16x16x32_bf16(a[rt], b[ct], acc[rt][ct], 0, 0, 0);
    }

    float* eb = sm.g.eb;   // aliases Ah — safe: barriers below separate all uses
    #pragma unroll 1
    for (int rt = 0; rt < 4; rt++){
        __syncthreads();
        #pragma unroll
        for (int ct = 0; ct < 4; ct++)
            #pragma unroll
            for (int reg = 0; reg < 4; reg++)
                eb[(quad*4 + reg)*RSS + (w*4 + ct)*CS + m_lo] = acc[rt][ct][reg];
        __syncthreads();
        int r = t >> 4, cb = t & 15;
        int c0 = cb * 16;
        int m = m0 + rt*16 + r;
        f32x4 v[4];
        #pragma unroll
        for (int p = 0; p < 4; p++) v[p] = *(const f32x4*)&eb[r*RSS + cb*CS + p*4];
        float ps = 0.f, pd = 0.f;
        #pragma unroll
        for (int p = 0; p < 4; p++)
            #pragma unroll
            for (int j = 0; j < 4; j++){
                ps += v[p][j] * att[c0 + p*4 + j];
                pd += v[p][j] * att[256 + c0 + p*4 + j];
            }
        if (m < N){
            short ov[16];
            #pragma unroll
            for (int p = 0; p < 4; p++)
                #pragma unroll
                for (int j = 0; j < 4; j++) ov[p*4+j] = bf16s(v[p][j]);
            *(bf16x8*)&h1[(size_t)m*256 + c0]     = *(const bf16x8*)&ov[0];
            *(bf16x8*)&h1[(size_t)m*256 + c0 + 8] = *(const bf16x8*)&ov[8];
        }
        ps += __shfl_xor(ps, 1);
        pd += __shfl_xor(pd, 1);
        if (((t & 1) == 0) && m < N){
            int hd = cb >> 1;
            a_s[m*8 + hd] = ps;
            a_d[m*8 + hd] = pd;
        }
    }
}

// ---------------- fine pass: per-bucket dst counts (wave-private), scan, self-loops, final scatter ----------------
__global__ __launch_bounds__(256) void k_fine(const int* __restrict__ bucketPtr,
        const int* __restrict__ pk, int* __restrict__ rowptr, int* __restrict__ srcs,
        int N){
    __shared__ int hist[4][256];
    __shared__ int cur[4][256];
    __shared__ int sd[256];
    int t = threadIdx.x;
    int wv = t >> 6, lane = t & 63;
    int b = blockIdx.x;
    int d0 = b << 8;
    int nd = N - d0; if (nd > 256) nd = 256; if (nd < 0) nd = 0;
    int ebeg = bucketPtr[b], eend = bucketPtr[b+1];
    int tot = eend - ebeg;
    int per = (tot + 3) >> 2;
    int wb = wv*per, we = wb + per;
    if (we > tot) we = tot;
    if (wb > tot) wb = tot;
    #pragma unroll
    for (int w = 0; w < 4; w++) hist[w][t] = 0;
    __syncthreads();
    for (int i = wb + lane; i < we; i += 64)
        atomicAdd(&hist[wv][((unsigned)pk[ebeg + i]) >> 24], 1);   // wave-private
    __syncthreads();
    int h0 = hist[0][t], h1 = hist[1][t], h2 = hist[2][t], h3 = hist[3][t];
    int selfc = (t < nd) ? 1 : 0;
    int v = selfc + h0 + h1 + h2 + h3;
    sd[t] = v;
    __syncthreads();
    #pragma unroll
    for (int off = 1; off < 256; off <<= 1){
        int a = (t >= off) ? sd[t - off] : 0;
        __syncthreads();
        sd[t] += a;
        __syncthreads();
    }
    int r = ebeg + d0 + sd[t] - v;   // prior self-loops = d0 (all earlier buckets full)
    if (t < nd){
        rowptr[d0 + t] = r;
        srcs[r] = d0 + t;            // self-loop at segment head
    }
    int c0 = r + selfc;
    cur[0][t] = c0;
    cur[1][t] = c0 + h0;
    cur[2][t] = c0 + h0 + h1;
    cur[3][t] = c0 + h0 + h1 + h2;
    __syncthreads();
    for (int i = wb + lane; i < we; i += 64){
        int p = pk[ebeg + i];
        int pos = atomicAdd(&cur[wv][((unsigned)p) >> 24], 1);     // wave-private
        srcs[pos] = p & 0xFFFFFF;
    }
}

// ---------------- layer-1: software-pipelined aggregate (srcs/a_s lookahead) + elu + bias ----------------
__global__ __launch_bounds__(256) void k_edge1(const int* __restrict__ rowptr,
        const int* __restrict__ srcs, const float* __restrict__ a_s,
        const float* __restrict__ a_d, const bf16* __restrict__ h1,
        const void* __restrict__ b1, bf16* __restrict__ x2,
        const int* __restrict__ flag, int N){
    int t = threadIdx.x;
    int lane = t & 63, wv = t >> 6;
    int n = blockIdx.x*4 + wv;
    if (n >= N) return;
    int beg = rowptr[n];
    int deg = rowptr[n+1] - beg;

    int cl = lane & 31;          // channel group: channels cl*8..cl*8+7
    int hb = cl >> 2;            // head of this group
    int half = lane >> 5;        // edge parity
    float adb = a_d[n*8 + hb];

    f32x2 acc2[4];
    #pragma unroll
    for (int k = 0; k < 4; k++) acc2[k] = (f32x2){0.f, 0.f};
    float z = 0.f;

    int e = half;
    if (e + 6 < deg){
        // prologue: indices + att values for chunk 0
        int s0 = srcs[beg + e];
        int s1 = srcs[beg + e + 2];
        int s2 = srcs[beg + e + 4];
        int s3 = srcs[beg + e + 6];
        float a0 = a_s[s0*8 + hb];
        float a1 = a_s[s1*8 + hb];
        float a2 = a_s[s2*8 + hb];
        float a3 = a_s[s3*8 + hb];
        while (true){
            // issue current h1 gathers (indices already resident)
            bf16x8 v0 = *(const bf16x8*)&h1[(size_t)s0*256 + cl*8];
            bf16x8 v1 = *(const bf16x8*)&h1[(size_t)s1*256 + cl*8];
            bf16x8 v2 = *(const bf16x8*)&h1[(size_t)s2*256 + cl*8];
            bf16x8 v3 = *(const bf16x8*)&h1[(size_t)s3*256 + cl*8];
            int en = e + 8;
            bool more = (en + 6 < deg);    // wave-uniform
            int n0, n1, n2, n3;
            float b0, b1, b2, b3;
            if (more){
                // lookahead: next chunk indices + att values fly under current compute
                n0 = srcs[beg + en];
                n1 = srcs[beg + en + 2];
                n2 = srcs[beg + en + 4];
                n3 = srcs[beg + en + 6];
                b0 = a_s[n0*8 + hb];
                b1 = a_s[n1*8 + hb];
                b2 = a_s[n2*8 + hb];
                b3 = a_s[n3*8 + hb];
            }
            // weights from resident att values (VALU overlaps gather latency)
            float w0 = __expf(fminf(lrelu(a0 + adb), 80.f));
            float w1 = __expf(fminf(lrelu(a1 + adb), 80.f));
            float w2 = __expf(fminf(lrelu(a2 + adb), 80.f));
            float w3 = __expf(fminf(lrelu(a3 + adb), 80.f));
            z += (w0 + w1) + (w2 + w3);
            acc8p(acc2, w0, v0);
            acc8p(acc2, w1, v1);
            acc8p(acc2, w2, v2);
            acc8p(acc2, w3, v3);
            e = en;
            if (!more) break;
            s0 = n0; s1 = n1; s2 = n2; s3 = n3;
            a0 = b0; a1 = b1; a2 = b2; a3 = b3;
        }
    }
    for (; e < deg; e += 2){
        int s = srcs[beg + e];
        float w = __expf(fminf(lrelu(a_s[s*8 + hb] + adb), 80.f));
        bf16x8 hv = *(const bf16x8*)&h1[(size_t)s*256 + cl*8];
        z += w;
        acc8p(acc2, w, hv);
    }
    float acc[8];
    #pragma unroll
    for (int k = 0; k < 4; k++){ acc[2*k] = acc2[k][0]; acc[2*k+1] = acc2[k][1]; }
    #pragma unroll
    for (int j = 0; j < 8; j++) acc[j] += __shfl_xor(acc[j], 32);
    z += __shfl_xor(z, 32);
    float rz = 1.f / (z + 1e-16f);

    if (half == 0){
        int isb = *flag;
        bf16x8 bv = load8(b1, cl*8, isb);
        short ov[8];
        #pragma unroll
        for (int j = 0; j < 8; j++){
            float v = acc[j] * rz + bfbits(bv[j]);
            ov[j] = bf16s(v > 0.f ? v : expm1f(v));
        }
        *(bf16x8*)&x2[(size_t)n*256 + cl*8] = *(const bf16x8*)ov;
    }
}

// ---------------- GEMM2 (MFMA) + attention scalars layer 2 ----------------
__global__ __launch_bounds__(256) void k_gemm2(const bf16* __restrict__ x2,
        const bf16* __restrict__ Bp2, const void* __restrict__ attS,
        const void* __restrict__ attD, float* __restrict__ h2,
        float* __restrict__ a2s, float* __restrict__ a2d,
        const int* __restrict__ flag, int N){
    int t = threadIdx.x;
    int isb = *flag;
    int w = t >> 6, lane = t & 63;
    int m_lo = lane & 15, quad = lane >> 4;
    int m0 = blockIdx.x*64 + w*16;
    int mr = m0 + m_lo; if (mr >= N) mr = N-1;
    f32x4 acc = (f32x4){0.f,0.f,0.f,0.f};
    #pragma unroll
    for (int kt = 0; kt < 8; kt++){
        bf16x8 a = *(const bf16x8*)&x2[(size_t)mr*256 + kt*32 + quad*8];
        bf16x8 b = *(const bf16x8*)&Bp2[(size_t)(kt*64 + lane)*8];
        acc = __builtin_amdgcn_mfma_f32_16x16x32_bf16(a, b, acc, 0, 0, 0);
    }
    float s2 = (m_lo < 8) ? cvtf(attS, m_lo, isb) : 0.f;
    float d2 = (m_lo < 8) ? cvtf(attD, m_lo, isb) : 0.f;
    #pragma unroll
    for (int reg = 0; reg < 4; reg++){
        int m = m0 + quad*4 + reg;
        float val = acc[reg];
        float ps = val * s2, pd = val * d2;
        ps += __shfl_xor(ps, 1); ps += __shfl_xor(ps, 2);
        ps += __shfl_xor(ps, 4); ps += __shfl_xor(ps, 8);
        pd += __shfl_xor(pd, 1); pd += __shfl_xor(pd, 2);
        pd += __shfl_xor(pd, 4); pd += __shfl_xor(pd, 8);
        if (m < N){
            if (m_lo < 8) h2[(size_t)m*8 + m_lo] = val;
            if (m_lo == 0){ a2s[m] = ps; a2d[m] = pd; }
        }
    }
}

// ---------------- layer-2: software-pipelined aggregate + bias + log_softmax ----------------
__global__ __launch_bounds__(256) void k_edge2(const int* __restrict__ rowptr,
        const int* __restrict__ srcs, const float* __restrict__ a2s,
        const float* __restrict__ a2d, const float* __restrict__ h2,
        const void* __restrict__ b2, void* __restrict__ outv,
        const int* __restrict__ flag, int N){
    int t = threadIdx.x;
    int lane = t & 63, wv = t >> 6;
    int n = blockIdx.x*4 + wv;
    if (n >= N) return;
    int beg = rowptr[n];
    int deg = rowptr[n+1] - beg;
    float adh = a2d[n];
    int ep = lane >> 3, c = lane & 7;
    float acc = 0.f, z = 0.f;
    int e = ep;
    if (e + 8 < deg){
        int s0 = srcs[beg + e];
        int s1 = srcs[beg + e + 8];
        float a0 = a2s[s0], a1 = a2s[s1];
        float g0 = h2[(size_t)s0*8 + c], g1 = h2[(size_t)s1*8 + c];
        while (true){
            int en = e + 16;
            bool more = (en + 8 < deg);    // wave-uniform
            int n0, n1; float b0, b1, f0, f1;
            if (more){
                n0 = srcs[beg + en];
                n1 = srcs[beg + en + 8];
                b0 = a2s[n0]; b1 = a2s[n1];
                f0 = h2[(size_t)n0*8 + c]; f1 = h2[(size_t)n1*8 + c];
            }
            float w0 = __expf(fminf(lrelu(a0 + adh), 80.f));
            float w1 = __expf(fminf(lrelu(a1 + adh), 80.f));
            z += w0 + w1;
            acc += w0 * g0 + w1 * g1;
            e = en;
            if (!more) break;
            s0 = n0; s1 = n1; a0 = b0; a1 = b1; g0 = f0; g1 = f1;
        }
    }
    for (; e < deg; e += 8){
        int s = srcs[beg + e];
        float w = __expf(fminf(lrelu(a2s[s] + adh), 80.f));
        z += w;
        acc += w * h2[(size_t)s*8 + c];
    }
    acc += __shfl_xor(acc, 8);
    acc += __shfl_xor(acc, 16);
    acc += __shfl_xor(acc, 32);
    z += __shfl_xor(z, 8);
    z += __shfl_xor(z, 16);
    z += __shfl_xor(z, 32);
    int isb = *flag;
    float val = acc / (z + 1e-16f) + cvtf(b2, c, isb);
    float mx = val;
    mx = fmaxf(mx, __shfl_xor(mx, 1));
    mx = fmaxf(mx, __shfl_xor(mx, 2));
    mx = fmaxf(mx, __shfl_xor(mx, 4));
    float se = __expf(val - mx);
    se += __shfl_xor(se, 1); se += __shfl_xor(se, 2); se += __shfl_xor(se, 4);
    float r = val - mx - __logf(se);
    if (lane < 8){
        if (isb) ((bf16*)outv)[(size_t)n*8 + c] = f2bf(r);
        else     ((float*)outv)[(size_t)n*8 + c] = r;
    }
}

extern "C" void kernel_launch(void* const* d_in, const int* in_sizes, int n_in,
                              void* d_out, int out_size, void* d_ws, size_t ws_size,
                              hipStream_t stream) {
    const int* ei = (const int*)d_in[2];
    const int N = in_sizes[0] / 128;
    const int E = in_sizes[2] / 2;
    const int ET = E + N;
    const int NBUK = (N + 255) >> 8;

    char* p = (char*)d_ws;
    auto alloc = [&](size_t bytes) -> void* {
        char* r = p;
        p += (bytes + 255) & ~(size_t)255;
        return (void*)r;
    };
    int*   flag      = (int*)  alloc(256);
    int*   bucketCnt = (int*)  alloc((size_t)NBUK*4);
    int*   bucketPtr = (int*)  alloc((size_t)(NBUK+1)*4);
    int*   bucketCur = (int*)  alloc((size_t)NBUK*16*4);   // strided: 1 int per 64B
    int*   rowptr    = (int*)  alloc((size_t)(N+1)*4);
    int*   srcs      = (int*)  alloc((size_t)ET*4);
    int*   pk        = (int*)  alloc((size_t)E*4);
    bf16*  Bp        = (bf16*) alloc((size_t)192*256*2);
    bf16*  Bp2       = (bf16*) alloc((size_t)8*64*8*2);
    bf16*  emb       = (bf16*) alloc((size_t)N*64*2);
    bf16*  h1        = (bf16*) alloc((size_t)N*256*2);
    float* a_s       = (float*)alloc((size_t)N*8*4);
    float* a_d       = (float*)alloc((size_t)N*8*4);
    bf16*  x2        = (bf16*) alloc((size_t)N*256*2);
    float* h2        = (float*)alloc((size_t)N*8*4);
    float* a2s       = (float*)alloc((size_t)N*4);
    float* a2d       = (float*)alloc((size_t)N*4);

    hipMemsetAsync(bucketCnt, 0, (size_t)NBUK*4, stream);
    {
        int nEmb  = (N + 127)/128;
        int nPack = (16*6*64*8 + 8*64*8 + 255)/256;
        int nCnt  = 256;
        k_prep<<<nEmb + nPack + nCnt, 256, 0, stream>>>(
                (const unsigned short*)d_in[0], d_in[1], d_in[3], d_in[4],
                d_in[5], d_in[9], emb, Bp, Bp2,
                ei + E, bucketCnt, flag, N, E, nEmb, nPack, nCnt, NBUK);
    }
    k_bscan<<<1, 256, 0, stream>>>(bucketCnt, bucketPtr, bucketCur, rowptr, N, E, NBUK);
    {
        int nG = (N + 63)/64;
        int nScat = (E + CHK - 1)/CHK;
        k_sg<<<nScat + nG, 256, 0, stream>>>(ei, bucketCur, pk,
                d_in[0], emb, Bp, d_in[6], d_in[7], h1, a_s, a_d, flag, N, E, nScat, NBUK);
    }
    k_fine<<<NBUK, 256, 0, stream>>>(bucketPtr, pk, rowptr, srcs, N);
    k_edge1<<<(N + 3)/4, 256, 0, stream>>>(rowptr, srcs, a_s, a_d, h1, d_in[8], x2, flag, N);
    k_gemm2<<<(N + 63)/64, 256, 0, stream>>>(x2, Bp2, d_in[10], d_in[11], h2, a2s, a2d, flag, N);
    k_edge2<<<(N + 3)/4, 256, 0, stream>>>(rowptr, srcs, a2s, a2d, h2, d_in[12], d_out, flag, N);
}